// Round 1
// baseline (1920.169 us; speedup 1.0000x reference)
//
#include <hip/hip_runtime.h>

#define N_NODES 100000
#define NEDGE   3200000
#define DIN     16
#define DIM     128
#define DOUT    16
#define LN_EPS  1e-5f

// ---------------- CSR build ----------------

__global__ __launch_bounds__(256) void k_zero(int* __restrict__ cnt) {
    int i = blockIdx.x * 256 + threadIdx.x;
    if (i < N_NODES) cnt[i] = 0;
}

__global__ __launch_bounds__(256) void k_count(const int* __restrict__ col, int* __restrict__ cnt) {
    int i = blockIdx.x * 256 + threadIdx.x;
    if (i < NEDGE) atomicAdd(&cnt[col[i]], 1);
}

// single block: exclusive scan of cnt -> indptr, dinv = rsqrt(deg+1), zero cnt for reuse
__global__ __launch_bounds__(1024) void k_scan(int* __restrict__ cnt, int* __restrict__ indptr,
                                               float* __restrict__ dinv) {
    __shared__ int sums[1024];
    int t = threadIdx.x;
    const int C = (N_NODES + 1023) / 1024;  // 98
    int lo = t * C, hi = lo + C;
    if (lo > N_NODES) lo = N_NODES;
    if (hi > N_NODES) hi = N_NODES;
    int s = 0;
    for (int i = lo; i < hi; i++) s += cnt[i];
    sums[t] = s;
    __syncthreads();
    for (int off = 1; off < 1024; off <<= 1) {
        int v = sums[t];
        int a = (t >= off) ? sums[t - off] : 0;
        __syncthreads();
        sums[t] = v + a;
        __syncthreads();
    }
    int run = (t == 0) ? 0 : sums[t - 1];
    for (int i = lo; i < hi; i++) {
        int c = cnt[i];
        cnt[i] = 0;                       // reset cursor for k_fill
        indptr[i] = run;
        dinv[i] = rsqrtf((float)(c + 1)); // +1 self loop; always > 0
        run += c;
    }
    if (t == 1023) indptr[N_NODES] = run;
}

__global__ __launch_bounds__(256) void k_fill(const int* __restrict__ row, const int* __restrict__ col,
                                              const int* __restrict__ indptr, int* __restrict__ cnt,
                                              int* __restrict__ rows_s) {
    int i = blockIdx.x * 256 + threadIdx.x;
    if (i < NEDGE) {
        int c = col[i];
        int p = atomicAdd(&cnt[c], 1);
        rows_s[indptr[c] + p] = row[i];
    }
}

// ---------------- encoder: x = relu(X@W0+b0)@W1+b1 ----------------

__global__ __launch_bounds__(256) void k_enc(const float* __restrict__ X,
                                             const float* __restrict__ W0, const float* __restrict__ b0,
                                             const float* __restrict__ W1, const float* __restrict__ b1,
                                             float* __restrict__ xo) {
    __shared__ float W0s[DIN * DIM];   // 8 KB
    __shared__ float W1s[DIM * DIM];   // 64 KB
    __shared__ float b0s[DIM];
    __shared__ float b1s[DIM];
    __shared__ float Xs[8 * DIN];
    __shared__ float ts[8 * DIM];
    int tid = threadIdx.x;
    for (int i = tid; i < DIN * DIM / 4; i += 256) ((float4*)W0s)[i] = ((const float4*)W0)[i];
    for (int i = tid; i < DIM * DIM / 4; i += 256) ((float4*)W1s)[i] = ((const float4*)W1)[i];
    if (tid < DIM) { b0s[tid] = b0[tid]; b1s[tid] = b1[tid]; }
    int j2 = (tid & 63) * 2;
    int slot = tid >> 6;           // 4 waves, 2 nodes each
    int na = slot * 2, nb = na + 1;
    const int ngroups = N_NODES / 8;
    for (int g = blockIdx.x; g < ngroups; g += gridDim.x) {
        int n0 = g * 8;
        __syncthreads();
        if (tid < 8 * DIN) Xs[tid] = X[(size_t)n0 * DIN + tid];
        __syncthreads();
        float a0 = b0s[j2], a1 = b0s[j2 + 1], a2 = b0s[j2], a3 = b0s[j2 + 1];
        for (int i = 0; i < DIN; i++) {
            float2 w = *(const float2*)&W0s[i * DIM + j2];
            float xa = Xs[na * DIN + i], xb = Xs[nb * DIN + i];
            a0 += xa * w.x; a1 += xa * w.y; a2 += xb * w.x; a3 += xb * w.y;
        }
        ts[na * DIM + j2] = fmaxf(a0, 0.f); ts[na * DIM + j2 + 1] = fmaxf(a1, 0.f);
        ts[nb * DIM + j2] = fmaxf(a2, 0.f); ts[nb * DIM + j2 + 1] = fmaxf(a3, 0.f);
        __syncthreads();
        float c0 = b1s[j2], c1 = b1s[j2 + 1], c2 = b1s[j2], c3 = b1s[j2 + 1];
        for (int i = 0; i < DIM; i++) {
            float2 w = *(const float2*)&W1s[i * DIM + j2];
            float ta = ts[na * DIM + i], tb = ts[nb * DIM + i];
            c0 += ta * w.x; c1 += ta * w.y; c2 += tb * w.x; c3 += tb * w.y;
        }
        *(float2*)&xo[(size_t)(n0 + na) * DIM + j2] = make_float2(c0, c1);
        *(float2*)&xo[(size_t)(n0 + nb) * DIM + j2] = make_float2(c2, c3);
    }
}

// ---------------- conv GEMM: hs = (x @ W_conv) * dinv[node] ----------------

__global__ __launch_bounds__(256) void k_conv(const float* __restrict__ xi,
                                              const float* __restrict__ W,
                                              const float* __restrict__ dinv,
                                              float* __restrict__ hs) {
    __shared__ float Ws[DIM * DIM];    // 64 KB
    __shared__ float xs[16 * DIM];     // 8 KB
    int tid = threadIdx.x;
    for (int i = tid; i < DIM * DIM / 4; i += 256) ((float4*)Ws)[i] = ((const float4*)W)[i];
    int j2 = (tid & 63) * 2;
    int slot = tid >> 6;               // 4 waves, 4 nodes each
    int na = slot * 4;
    const int ngroups = N_NODES / 16;
    for (int g = blockIdx.x; g < ngroups; g += gridDim.x) {
        int n0 = g * 16;
        __syncthreads();
        for (int i = tid; i < 16 * DIM / 4; i += 256)
            ((float4*)xs)[i] = ((const float4*)(xi + (size_t)n0 * DIM))[i];
        __syncthreads();
        float a0x = 0, a0y = 0, a1x = 0, a1y = 0, a2x = 0, a2y = 0, a3x = 0, a3y = 0;
        for (int i = 0; i < DIM; i++) {
            float2 w = *(const float2*)&Ws[i * DIM + j2];
            float x0 = xs[(na + 0) * DIM + i];
            float x1 = xs[(na + 1) * DIM + i];
            float x2 = xs[(na + 2) * DIM + i];
            float x3 = xs[(na + 3) * DIM + i];
            a0x += x0 * w.x; a0y += x0 * w.y;
            a1x += x1 * w.x; a1y += x1 * w.y;
            a2x += x2 * w.x; a2y += x2 * w.y;
            a3x += x3 * w.x; a3y += x3 * w.y;
        }
        float d0 = dinv[n0 + na + 0], d1 = dinv[n0 + na + 1];
        float d2 = dinv[n0 + na + 2], d3 = dinv[n0 + na + 3];
        *(float2*)&hs[(size_t)(n0 + na + 0) * DIM + j2] = make_float2(a0x * d0, a0y * d0);
        *(float2*)&hs[(size_t)(n0 + na + 1) * DIM + j2] = make_float2(a1x * d1, a1y * d1);
        *(float2*)&hs[(size_t)(n0 + na + 2) * DIM + j2] = make_float2(a2x * d2, a2y * d2);
        *(float2*)&hs[(size_t)(n0 + na + 3) * DIM + j2] = make_float2(a3x * d3, a3y * d3);
    }
}

// ---------------- fused gather + residual + bias + LayerNorm ----------------
// one wave per node; lane holds float2 (cols 2l, 2l+1)

__global__ __launch_bounds__(256) void k_agg_ln(const float* __restrict__ hs, float* __restrict__ x,
                                                const float* __restrict__ dinv,
                                                const int* __restrict__ indptr,
                                                const int* __restrict__ rows_s,
                                                const float* __restrict__ bconv,
                                                const float* __restrict__ g_, const float* __restrict__ b_) {
    int v = (blockIdx.x * blockDim.x + threadIdx.x) >> 6;
    int lane = threadIdx.x & 63;
    if (v >= N_NODES) return;
    const float2* hs2 = (const float2*)hs;
    int beg = indptr[v], end = indptr[v + 1];
    float accx, accy;
    { float2 a = hs2[(size_t)v * 64 + lane]; accx = a.x; accy = a.y; }   // self loop
    for (int base = beg; base < end; base += 64) {
        int m = end - base; if (m > 64) m = 64;
        int r0 = rows_s[base + (lane < m ? lane : m - 1)];
        int k = 0;
        for (; k + 4 <= m; k += 4) {
            int ra = __shfl(r0, k), rb = __shfl(r0, k + 1);
            int rc = __shfl(r0, k + 2), rd = __shfl(r0, k + 3);
            float2 A = hs2[(size_t)ra * 64 + lane];
            float2 B = hs2[(size_t)rb * 64 + lane];
            float2 C = hs2[(size_t)rc * 64 + lane];
            float2 D = hs2[(size_t)rd * 64 + lane];
            accx += A.x + B.x + C.x + D.x;
            accy += A.y + B.y + C.y + D.y;
        }
        for (; k < m; k++) {
            int r = __shfl(r0, k);
            float2 A = hs2[(size_t)r * 64 + lane];
            accx += A.x; accy += A.y;
        }
    }
    float dv = dinv[v];
    float2 xv = ((const float2*)x)[(size_t)v * 64 + lane];
    float2 bc = ((const float2*)bconv)[lane];
    float yx = xv.x + dv * accx + bc.x;
    float yy = xv.y + dv * accy + bc.y;
    float s = yx + yy, s2 = yx * yx + yy * yy;
    for (int off = 32; off > 0; off >>= 1) {
        s += __shfl_down(s, off);
        s2 += __shfl_down(s2, off);
    }
    float mu = __shfl(s, 0) * (1.f / 128.f);
    float ms = __shfl(s2, 0) * (1.f / 128.f);
    float rstd = rsqrtf(ms - mu * mu + LN_EPS);
    float2 gg = ((const float2*)g_)[lane];
    float2 bb = ((const float2*)b_)[lane];
    float ox = (yx - mu) * rstd * gg.x + bb.x;
    float oy = (yy - mu) * rstd * gg.y + bb.y;
    ((float2*)x)[(size_t)v * 64 + lane] = make_float2(ox, oy);
}

// ---------------- decoder: out = relu(x@W0+b0)@W1+b1 ----------------

__global__ __launch_bounds__(256) void k_dec(const float* __restrict__ xi,
                                             const float* __restrict__ W0, const float* __restrict__ b0,
                                             const float* __restrict__ W1, const float* __restrict__ b1,
                                             float* __restrict__ out) {
    __shared__ float W0s[DIM * DIM];    // 64 KB
    __shared__ float W1s[DIM * DOUT];   // 8 KB
    __shared__ float b0s[DIM];
    __shared__ float b1s[DOUT];
    __shared__ float xs[4 * DIM];
    __shared__ float ts[4 * DIM];
    int tid = threadIdx.x;
    for (int i = tid; i < DIM * DIM / 4; i += 256) ((float4*)W0s)[i] = ((const float4*)W0)[i];
    for (int i = tid; i < DIM * DOUT / 4; i += 256) ((float4*)W1s)[i] = ((const float4*)W1)[i];
    if (tid < DIM) b0s[tid] = b0[tid];
    if (tid < DOUT) b1s[tid] = b1[tid];
    int j2 = (tid & 63) * 2;
    int slot = tid >> 6;                // 4 waves, 1 node each
    const int ngroups = N_NODES / 4;
    for (int g = blockIdx.x; g < ngroups; g += gridDim.x) {
        int n0 = g * 4;
        __syncthreads();
        if (tid < 128) ((float4*)xs)[tid] = ((const float4*)(xi + (size_t)n0 * DIM))[tid];
        __syncthreads();
        float a0 = b0s[j2], a1 = b0s[j2 + 1];
        for (int i = 0; i < DIM; i++) {
            float2 w = *(const float2*)&W0s[i * DIM + j2];
            float xv = xs[slot * DIM + i];
            a0 += xv * w.x; a1 += xv * w.y;
        }
        ts[slot * DIM + j2] = fmaxf(a0, 0.f);
        ts[slot * DIM + j2 + 1] = fmaxf(a1, 0.f);
        __syncthreads();
        if (tid < 128) {
            int node = tid >> 5, c = tid & 15, half = (tid >> 4) & 1;
            float acc = 0.f;
            int ib = half * 64;
            for (int i = ib; i < ib + 64; i++) acc += ts[node * DIM + i] * W1s[i * DOUT + c];
            acc += __shfl_xor(acc, 16);
            if (!half) out[(size_t)(n0 + node) * DOUT + c] = acc + b1s[c];
        }
    }
}

// ---------------- launch ----------------

extern "C" void kernel_launch(void* const* d_in, const int* in_sizes, int n_in,
                              void* d_out, int out_size, void* d_ws, size_t ws_size,
                              hipStream_t stream) {
    const float* X      = (const float*)d_in[0];
    const float* W_enc0 = (const float*)d_in[1];
    const float* b_enc0 = (const float*)d_in[2];
    const float* W_enc1 = (const float*)d_in[3];
    const float* b_enc1 = (const float*)d_in[4];
    const float* W_conv = (const float*)d_in[5];
    const float* b_conv = (const float*)d_in[6];
    const float* ln_g   = (const float*)d_in[7];
    const float* ln_b   = (const float*)d_in[8];
    const float* W_dec0 = (const float*)d_in[9];
    const float* b_dec0 = (const float*)d_in[10];
    const float* W_dec1 = (const float*)d_in[11];
    const float* b_dec1 = (const float*)d_in[12];
    const int*   erow   = (const int*)d_in[13];         // edge_index[0] = sources
    const int*   ecol   = erow + NEDGE;                 // edge_index[1] = targets
    float* out = (float*)d_out;

    float* x      = (float*)d_ws;                       // N*128 f32
    float* hs     = x + (size_t)N_NODES * DIM;          // N*128 f32
    float* dinv   = hs + (size_t)N_NODES * DIM;         // N f32
    int*   cnt    = (int*)(dinv + N_NODES);             // N int
    int*   indptr = cnt + N_NODES;                      // N+1 int
    int*   rows_s = indptr + N_NODES + 8;               // E int

    // CSR build (per launch; d_ws is re-poisoned before every call)
    k_zero<<<(N_NODES + 255) / 256, 256, 0, stream>>>(cnt);
    k_count<<<(NEDGE + 255) / 256, 256, 0, stream>>>(ecol, cnt);
    k_scan<<<1, 1024, 0, stream>>>(cnt, indptr, dinv);
    k_fill<<<(NEDGE + 255) / 256, 256, 0, stream>>>(erow, ecol, indptr, cnt, rows_s);

    k_enc<<<512, 256, 0, stream>>>(X, W_enc0, b_enc0, W_enc1, b_enc1, x);

    for (int s = 0; s < 3; s++) {   // msg_steps = 3 (fixed scalar input)
        k_conv<<<512, 256, 0, stream>>>(x, W_conv, dinv, hs);
        k_agg_ln<<<N_NODES / 4, 256, 0, stream>>>(hs, x, dinv, indptr, rows_s, b_conv, ln_g, ln_b);
    }

    k_dec<<<512, 256, 0, stream>>>(x, W_dec0, b_dec0, W_dec1, b_dec1, out);
}

// Round 2
// 1206.124 us; speedup vs baseline: 1.5920x; 1.5920x over previous
//
#include <hip/hip_runtime.h>

#define N_NODES 100000
#define NEDGE   3200000
#define DIN     16
#define DIM     128
#define DOUT    16
#define LN_EPS  1e-5f
#define NBLK    391          // ceil(100000/256)

// ---- bf16 helpers (RNE pack, cheap unpack) ----
static __device__ __forceinline__ unsigned f2bf(float f) {
    unsigned u = __float_as_uint(f);
    return (u + 0x7fffu + ((u >> 16) & 1u)) >> 16;
}
static __device__ __forceinline__ float bf_lo(unsigned u) { return __uint_as_float(u << 16); }
static __device__ __forceinline__ float bf_hi(unsigned u) { return __uint_as_float(u & 0xFFFF0000u); }

// ---------------- CSR build (parallel two-level scan) ----------------

__global__ __launch_bounds__(256) void k_zero(int* __restrict__ cnt) {
    int i = blockIdx.x * 256 + threadIdx.x;
    if (i < N_NODES) cnt[i] = 0;
}

__global__ __launch_bounds__(256) void k_count(const int* __restrict__ col, int* __restrict__ cnt) {
    int i = blockIdx.x * 256 + threadIdx.x;
    if (i < NEDGE) atomicAdd(&cnt[col[i]], 1);
}

// per-block sum of 256 counts -> bsum[b]; also dinv = rsqrt(deg+1)
__global__ __launch_bounds__(256) void k_bsum(const int* __restrict__ cnt, int* __restrict__ bsum,
                                              float* __restrict__ dinv) {
    int i = blockIdx.x * 256 + threadIdx.x;
    int v = 0;
    if (i < N_NODES) {
        v = cnt[i];
        dinv[i] = rsqrtf((float)(v + 1));   // +1 self loop, always > 0
    }
    int s = v;
    for (int off = 32; off > 0; off >>= 1) s += __shfl_down(s, off);
    __shared__ int ws4[4];
    if ((threadIdx.x & 63) == 0) ws4[threadIdx.x >> 6] = s;
    __syncthreads();
    if (threadIdx.x == 0) bsum[blockIdx.x] = ws4[0] + ws4[1] + ws4[2] + ws4[3];
}

// single small block: exclusive scan of 391 block sums
__global__ __launch_bounds__(512) void k_bscan(const int* __restrict__ bsum, int* __restrict__ boff) {
    __shared__ int sh[512];
    int t = threadIdx.x;
    int v = (t < NBLK) ? bsum[t] : 0;
    sh[t] = v;
    __syncthreads();
    for (int off = 1; off < 512; off <<= 1) {
        int a = (t >= off) ? sh[t - off] : 0;
        __syncthreads();
        sh[t] += a;
        __syncthreads();
    }
    if (t < NBLK) boff[t] = sh[t] - v;
}

// parallel indptr write-out: intra-block scan + block offset; zero cnt for k_fill cursor
__global__ __launch_bounds__(256) void k_indptr(int* __restrict__ cnt, const int* __restrict__ boff,
                                                int* __restrict__ indptr) {
    int i = blockIdx.x * 256 + threadIdx.x;
    int lane = threadIdx.x & 63, w = threadIdx.x >> 6;
    int v = (i < N_NODES) ? cnt[i] : 0;
    int s = v;
    for (int off = 1; off < 64; off <<= 1) {
        int t = __shfl_up(s, off);
        if (lane >= off) s += t;
    }
    __shared__ int wsum[4];
    if (lane == 63) wsum[w] = s;
    __syncthreads();
    int add = boff[blockIdx.x];
    for (int k = 0; k < w; k++) add += wsum[k];
    int excl = add + s - v;
    if (i < N_NODES) {
        indptr[i] = excl;
        cnt[i] = 0;
        if (i == N_NODES - 1) indptr[N_NODES] = excl + v;
    }
}

__global__ __launch_bounds__(256) void k_fill(const int* __restrict__ row, const int* __restrict__ col,
                                              const int* __restrict__ indptr, int* __restrict__ cnt,
                                              int* __restrict__ rows_s) {
    int i = blockIdx.x * 256 + threadIdx.x;
    if (i < NEDGE) {
        int c = col[i];
        int p = atomicAdd(&cnt[c], 1);
        rows_s[indptr[c] + p] = row[i];
    }
}

// ---------------- encoder: x = relu(X@W0+b0)@W1+b1 ----------------
// 16 nodes/block, 4 waves x 4 nodes; broadcast float4 x-reads

__global__ __launch_bounds__(256) void k_enc(const float* __restrict__ X,
                                             const float* __restrict__ W0, const float* __restrict__ b0,
                                             const float* __restrict__ W1, const float* __restrict__ b1,
                                             float* __restrict__ xo) {
    __shared__ float W0s[DIN * DIM];   // 8 KB
    __shared__ float W1s[DIM * DIM];   // 64 KB
    __shared__ float b0s[DIM], b1s[DIM];
    __shared__ float Xs[16 * DIN];
    __shared__ float ts[16 * DIM];     // 8 KB
    int tid = threadIdx.x;
    for (int i = tid; i < DIN * DIM / 4; i += 256) ((float4*)W0s)[i] = ((const float4*)W0)[i];
    for (int i = tid; i < DIM * DIM / 4; i += 256) ((float4*)W1s)[i] = ((const float4*)W1)[i];
    if (tid < DIM) { b0s[tid] = b0[tid]; b1s[tid] = b1[tid]; }
    int lane = tid & 63, wv = tid >> 6;
    int j2 = lane * 2;
    int na = wv * 4;
    const int ngroups = N_NODES / 16;
    for (int g = blockIdx.x; g < ngroups; g += gridDim.x) {
        int n0 = g * 16;
        __syncthreads();
        if (tid < 64) ((float4*)Xs)[tid] = ((const float4*)(X + (size_t)n0 * DIN))[tid];
        __syncthreads();
        float2 a[4];
        #pragma unroll
        for (int nd = 0; nd < 4; nd++) a[nd] = make_float2(b0s[j2], b0s[j2 + 1]);
        for (int i = 0; i < DIN; i += 4) {
            float4 xv[4];
            #pragma unroll
            for (int nd = 0; nd < 4; nd++) xv[nd] = *(const float4*)&Xs[(na + nd) * DIN + i];
            #pragma unroll
            for (int k = 0; k < 4; k++) {
                float2 w = *(const float2*)&W0s[(i + k) * DIM + j2];
                #pragma unroll
                for (int nd = 0; nd < 4; nd++) {
                    float f = ((const float*)&xv[nd])[k];
                    a[nd].x += f * w.x; a[nd].y += f * w.y;
                }
            }
        }
        #pragma unroll
        for (int nd = 0; nd < 4; nd++) {
            ts[(na + nd) * DIM + j2]     = fmaxf(a[nd].x, 0.f);
            ts[(na + nd) * DIM + j2 + 1] = fmaxf(a[nd].y, 0.f);
        }
        __syncthreads();
        float2 c[4];
        #pragma unroll
        for (int nd = 0; nd < 4; nd++) c[nd] = make_float2(b1s[j2], b1s[j2 + 1]);
        for (int i = 0; i < DIM; i += 4) {
            float4 tv[4];
            #pragma unroll
            for (int nd = 0; nd < 4; nd++) tv[nd] = *(const float4*)&ts[(na + nd) * DIM + i];
            #pragma unroll
            for (int k = 0; k < 4; k++) {
                float2 w = *(const float2*)&W1s[(i + k) * DIM + j2];
                #pragma unroll
                for (int nd = 0; nd < 4; nd++) {
                    float f = ((const float*)&tv[nd])[k];
                    c[nd].x += f * w.x; c[nd].y += f * w.y;
                }
            }
        }
        #pragma unroll
        for (int nd = 0; nd < 4; nd++)
            *(float2*)&xo[(size_t)(n0 + na + nd) * DIM + j2] = c[nd];
    }
}

// ---------------- conv GEMM: hs_bf16 = pack_bf16((x @ W_conv) * dinv[node]) ----------------

__global__ __launch_bounds__(256) void k_conv(const float* __restrict__ xi,
                                              const float* __restrict__ W,
                                              const float* __restrict__ dinv,
                                              unsigned* __restrict__ hs) {
    __shared__ float Ws[DIM * DIM];    // 64 KB
    __shared__ float xs[16 * DIM];     // 8 KB
    int tid = threadIdx.x;
    for (int i = tid; i < DIM * DIM / 4; i += 256) ((float4*)Ws)[i] = ((const float4*)W)[i];
    int lane = tid & 63, wv = tid >> 6;
    int j2 = lane * 2;
    int na = wv * 4;
    const int ngroups = N_NODES / 16;
    for (int g = blockIdx.x; g < ngroups; g += gridDim.x) {
        int n0 = g * 16;
        __syncthreads();
        for (int i = tid; i < 16 * DIM / 4; i += 256)
            ((float4*)xs)[i] = ((const float4*)(xi + (size_t)n0 * DIM))[i];
        __syncthreads();
        float2 acc[4] = {{0,0},{0,0},{0,0},{0,0}};
        for (int i = 0; i < DIM; i += 4) {
            float4 xv[4];
            #pragma unroll
            for (int nd = 0; nd < 4; nd++) xv[nd] = *(const float4*)&xs[(na + nd) * DIM + i];
            #pragma unroll
            for (int k = 0; k < 4; k++) {
                float2 w = *(const float2*)&Ws[(i + k) * DIM + j2];
                #pragma unroll
                for (int nd = 0; nd < 4; nd++) {
                    float f = ((const float*)&xv[nd])[k];
                    acc[nd].x += f * w.x; acc[nd].y += f * w.y;
                }
            }
        }
        #pragma unroll
        for (int nd = 0; nd < 4; nd++) {
            float d = dinv[n0 + na + nd];
            unsigned pack = f2bf(acc[nd].x * d) | (f2bf(acc[nd].y * d) << 16);
            hs[(size_t)(n0 + na + nd) * 64 + lane] = pack;
        }
    }
}

// ---------------- fused gather + residual + bias + LayerNorm ----------------
// one wave per node; lane holds cols (2l, 2l+1); hs is packed bf16x2

__global__ __launch_bounds__(256) void k_agg_ln(const unsigned* __restrict__ hs, float* __restrict__ x,
                                                const float* __restrict__ dinv,
                                                const int* __restrict__ indptr,
                                                const int* __restrict__ rows_s,
                                                const float* __restrict__ bconv,
                                                const float* __restrict__ g_, const float* __restrict__ b_) {
    int v = (blockIdx.x * blockDim.x + threadIdx.x) >> 6;
    int lane = threadIdx.x & 63;
    if (v >= N_NODES) return;
    int beg = indptr[v], end = indptr[v + 1];
    float accx, accy;
    { unsigned u = hs[(size_t)v * 64 + lane]; accx = bf_lo(u); accy = bf_hi(u); }  // self loop
    for (int base = beg; base < end; base += 64) {
        int m = end - base; if (m > 64) m = 64;
        int r0 = rows_s[base + (lane < m ? lane : m - 1)];
        int k = 0;
        for (; k + 4 <= m; k += 4) {
            int ra = __shfl(r0, k), rb = __shfl(r0, k + 1);
            int rc = __shfl(r0, k + 2), rd = __shfl(r0, k + 3);
            unsigned A = hs[(size_t)ra * 64 + lane];
            unsigned B = hs[(size_t)rb * 64 + lane];
            unsigned C = hs[(size_t)rc * 64 + lane];
            unsigned D = hs[(size_t)rd * 64 + lane];
            accx += bf_lo(A) + bf_lo(B) + bf_lo(C) + bf_lo(D);
            accy += bf_hi(A) + bf_hi(B) + bf_hi(C) + bf_hi(D);
        }
        for (; k < m; k++) {
            int r = __shfl(r0, k);
            unsigned A = hs[(size_t)r * 64 + lane];
            accx += bf_lo(A); accy += bf_hi(A);
        }
    }
    float dv = dinv[v];
    float2 xv = ((const float2*)x)[(size_t)v * 64 + lane];
    float2 bc = ((const float2*)bconv)[lane];
    float yx = xv.x + dv * accx + bc.x;
    float yy = xv.y + dv * accy + bc.y;
    float s = yx + yy, s2 = yx * yx + yy * yy;
    for (int off = 32; off > 0; off >>= 1) {
        s += __shfl_down(s, off);
        s2 += __shfl_down(s2, off);
    }
    float mu = __shfl(s, 0) * (1.f / 128.f);
    float ms = __shfl(s2, 0) * (1.f / 128.f);
    float rstd = rsqrtf(ms - mu * mu + LN_EPS);
    float2 gg = ((const float2*)g_)[lane];
    float2 bb = ((const float2*)b_)[lane];
    float ox = (yx - mu) * rstd * gg.x + bb.x;
    float oy = (yy - mu) * rstd * gg.y + bb.y;
    ((float2*)x)[(size_t)v * 64 + lane] = make_float2(ox, oy);
}

// ---------------- decoder: out = relu(x@W0+b0)@W1+b1 ----------------
// 16 nodes/block; layer1 conv-style; layer2 one output/thread (padded ts, conflict-free)

#define TSD 136   // padded ts stride (floats): keeps float4 alignment, spreads banks

__global__ __launch_bounds__(256) void k_dec(const float* __restrict__ xi,
                                             const float* __restrict__ W0, const float* __restrict__ b0,
                                             const float* __restrict__ W1, const float* __restrict__ b1,
                                             float* __restrict__ out) {
    __shared__ float W0s[DIM * DIM];    // 64 KB
    __shared__ float W1s[DIM * DOUT];   // 8 KB
    __shared__ float b0s[DIM], b1s[DOUT];
    __shared__ float xs[16 * DIM];      // 8 KB
    __shared__ float ts[16 * TSD];
    int tid = threadIdx.x;
    for (int i = tid; i < DIM * DIM / 4; i += 256) ((float4*)W0s)[i] = ((const float4*)W0)[i];
    for (int i = tid; i < DIM * DOUT / 4; i += 256) ((float4*)W1s)[i] = ((const float4*)W1)[i];
    if (tid < DIM) b0s[tid] = b0[tid];
    if (tid < DOUT) b1s[tid] = b1[tid];
    int lane = tid & 63, wv = tid >> 6;
    int j2 = lane * 2;
    int na = wv * 4;
    const int ngroups = N_NODES / 16;
    for (int g = blockIdx.x; g < ngroups; g += gridDim.x) {
        int n0 = g * 16;
        __syncthreads();
        for (int i = tid; i < 16 * DIM / 4; i += 256)
            ((float4*)xs)[i] = ((const float4*)(xi + (size_t)n0 * DIM))[i];
        __syncthreads();
        float2 a[4];
        #pragma unroll
        for (int nd = 0; nd < 4; nd++) a[nd] = make_float2(b0s[j2], b0s[j2 + 1]);
        for (int i = 0; i < DIM; i += 4) {
            float4 xv[4];
            #pragma unroll
            for (int nd = 0; nd < 4; nd++) xv[nd] = *(const float4*)&xs[(na + nd) * DIM + i];
            #pragma unroll
            for (int k = 0; k < 4; k++) {
                float2 w = *(const float2*)&W0s[(i + k) * DIM + j2];
                #pragma unroll
                for (int nd = 0; nd < 4; nd++) {
                    float f = ((const float*)&xv[nd])[k];
                    a[nd].x += f * w.x; a[nd].y += f * w.y;
                }
            }
        }
        #pragma unroll
        for (int nd = 0; nd < 4; nd++) {
            ts[(na + nd) * TSD + j2]     = fmaxf(a[nd].x, 0.f);
            ts[(na + nd) * TSD + j2 + 1] = fmaxf(a[nd].y, 0.f);
        }
        __syncthreads();
        {   // layer2: 256 threads = 16 nodes x 16 cols
            int node = tid >> 4, c = tid & 15;
            float acc = b1s[c];
            for (int i = 0; i < DIM; i++)
                acc += ts[node * TSD + i] * W1s[i * DOUT + c];
            out[(size_t)(n0 + node) * DOUT + c] = acc;
        }
    }
}

// ---------------- launch ----------------

extern "C" void kernel_launch(void* const* d_in, const int* in_sizes, int n_in,
                              void* d_out, int out_size, void* d_ws, size_t ws_size,
                              hipStream_t stream) {
    const float* X      = (const float*)d_in[0];
    const float* W_enc0 = (const float*)d_in[1];
    const float* b_enc0 = (const float*)d_in[2];
    const float* W_enc1 = (const float*)d_in[3];
    const float* b_enc1 = (const float*)d_in[4];
    const float* W_conv = (const float*)d_in[5];
    const float* b_conv = (const float*)d_in[6];
    const float* ln_g   = (const float*)d_in[7];
    const float* ln_b   = (const float*)d_in[8];
    const float* W_dec0 = (const float*)d_in[9];
    const float* b_dec0 = (const float*)d_in[10];
    const float* W_dec1 = (const float*)d_in[11];
    const float* b_dec1 = (const float*)d_in[12];
    const int*   erow   = (const int*)d_in[13];         // edge_index[0] = sources
    const int*   ecol   = erow + NEDGE;                 // edge_index[1] = targets
    float* out = (float*)d_out;

    float*    x      = (float*)d_ws;                            // N*128 f32
    unsigned* hs     = (unsigned*)(x + (size_t)N_NODES * DIM);  // N*64 u32 (bf16x2)
    float*    dinv   = (float*)(hs + (size_t)N_NODES * 64);     // N f32
    int*      cnt    = (int*)(dinv + N_NODES);                  // N int
    int*      indptr = cnt + N_NODES;                           // N+1 int
    int*      bsum   = indptr + N_NODES + 8;                    // NBLK
    int*      boff   = bsum + NBLK + 8;                         // NBLK
    int*      rows_s = boff + NBLK + 8;                         // E int

    // CSR build (per launch; d_ws is re-poisoned before every call)
    k_zero  <<<NBLK, 256, 0, stream>>>(cnt);
    k_count <<<(NEDGE + 255) / 256, 256, 0, stream>>>(ecol, cnt);
    k_bsum  <<<NBLK, 256, 0, stream>>>(cnt, bsum, dinv);
    k_bscan <<<1, 512, 0, stream>>>(bsum, boff);
    k_indptr<<<NBLK, 256, 0, stream>>>(cnt, boff, indptr);
    k_fill  <<<(NEDGE + 255) / 256, 256, 0, stream>>>(erow, ecol, indptr, cnt, rows_s);

    k_enc<<<512, 256, 0, stream>>>(X, W_enc0, b_enc0, W_enc1, b_enc1, x);

    for (int s = 0; s < 3; s++) {   // msg_steps = 3 (fixed scalar input)
        k_conv<<<512, 256, 0, stream>>>(x, W_conv, dinv, hs);
        k_agg_ln<<<N_NODES / 4, 256, 0, stream>>>(hs, x, dinv, indptr, rows_s, b_conv, ln_g, ln_b);
    }

    k_dec<<<512, 256, 0, stream>>>(x, W_dec0, b_dec0, W_dec1, b_dec1, out);
}

// Round 3
// 1114.965 us; speedup vs baseline: 1.7222x; 1.0818x over previous
//
#include <hip/hip_runtime.h>

#define N_NODES 100000
#define NEDGE   3200000
#define DIN     16
#define DIM     128
#define DOUT    16
#define LN_EPS  1e-5f
#define NBLK    391          // ceil(100000/256) scan blocks
#define NBINS   391          // 256-target bins: bin = c >> 8
#define CHUNK   16384        // edges per pass-B block
#define NPB     196          // ceil(NEDGE / CHUNK)

// ---- bf16 helpers (RNE pack, cheap unpack) ----
static __device__ __forceinline__ unsigned f2bf(float f) {
    unsigned u = __float_as_uint(f);
    return (u + 0x7fffu + ((u >> 16) & 1u)) >> 16;
}
static __device__ __forceinline__ float bf_lo(unsigned u) { return __uint_as_float(u << 16); }
static __device__ __forceinline__ float bf_hi(unsigned u) { return __uint_as_float(u & 0xFFFF0000u); }

// ---------------- CSR build ----------------

__global__ __launch_bounds__(256) void k_zero(int* __restrict__ cnt) {
    int i = blockIdx.x * 256 + threadIdx.x;
    if (i < N_NODES) cnt[i] = 0;
}

__global__ __launch_bounds__(256) void k_count(const int* __restrict__ col, int* __restrict__ cnt) {
    int i = blockIdx.x * 256 + threadIdx.x;
    if (i < NEDGE) atomicAdd(&cnt[col[i]], 1);
}

// per-block sum of 256 counts -> bsum[b]; also dinv = rsqrt(deg+1)
__global__ __launch_bounds__(256) void k_bsum(const int* __restrict__ cnt, int* __restrict__ bsum,
                                              float* __restrict__ dinv) {
    int i = blockIdx.x * 256 + threadIdx.x;
    int v = 0;
    if (i < N_NODES) {
        v = cnt[i];
        dinv[i] = rsqrtf((float)(v + 1));   // +1 self loop, always > 0
    }
    int s = v;
    for (int off = 32; off > 0; off >>= 1) s += __shfl_down(s, off);
    __shared__ int ws4[4];
    if ((threadIdx.x & 63) == 0) ws4[threadIdx.x >> 6] = s;
    __syncthreads();
    if (threadIdx.x == 0) bsum[blockIdx.x] = ws4[0] + ws4[1] + ws4[2] + ws4[3];
}

// single small block: exclusive scan of 391 block sums
__global__ __launch_bounds__(512) void k_bscan(const int* __restrict__ bsum, int* __restrict__ boff) {
    __shared__ int sh[512];
    int t = threadIdx.x;
    int v = (t < NBLK) ? bsum[t] : 0;
    sh[t] = v;
    __syncthreads();
    for (int off = 1; off < 512; off <<= 1) {
        int a = (t >= off) ? sh[t - off] : 0;
        __syncthreads();
        sh[t] += a;
        __syncthreads();
    }
    if (t < NBLK) boff[t] = sh[t] - v;
}

// parallel indptr write-out; zero cnt; init per-bin write cursors (bin = node >> 8)
__global__ __launch_bounds__(256) void k_indptr(int* __restrict__ cnt, const int* __restrict__ boff,
                                                int* __restrict__ indptr, int* __restrict__ bincur) {
    int i = blockIdx.x * 256 + threadIdx.x;
    int lane = threadIdx.x & 63, w = threadIdx.x >> 6;
    int v = (i < N_NODES) ? cnt[i] : 0;
    int s = v;
    for (int off = 1; off < 64; off <<= 1) {
        int t = __shfl_up(s, off);
        if (lane >= off) s += t;
    }
    __shared__ int wsum[4];
    if (lane == 63) wsum[w] = s;
    __syncthreads();
    int add = boff[blockIdx.x];
    for (int k = 0; k < w; k++) add += wsum[k];
    int excl = add + s - v;
    if (i < N_NODES) {
        indptr[i] = excl;
        cnt[i] = 0;
        if ((i & 255) == 0) bincur[i >> 8] = excl;
        if (i == N_NODES - 1) indptr[N_NODES] = excl + v;
    }
}

// pass B: bin edges into 391 per-target-range regions as packed pairs.
// Per-chunk LDS histogram + one global cursor bump per (block,bin) => each block
// owns a contiguous ~42-pair range => full-line write assembly in its XCD L2.
__global__ __launch_bounds__(256) void k_binpass(const int* __restrict__ row, const int* __restrict__ col,
                                                 int* __restrict__ bincur, unsigned* __restrict__ pairs) {
    __shared__ int lhist[NBINS], lbase[NBINS], lofs[NBINS];
    int tid = threadIdx.x;
    for (int b = tid; b < NBINS; b += 256) { lhist[b] = 0; lofs[b] = 0; }
    __syncthreads();
    int e0 = blockIdx.x * CHUNK;
    int e1 = e0 + CHUNK; if (e1 > NEDGE) e1 = NEDGE;
    for (int e = e0 + tid; e < e1; e += 256)
        atomicAdd(&lhist[col[e] >> 8], 1);
    __syncthreads();
    for (int b = tid; b < NBINS; b += 256) {
        int h = lhist[b];
        lbase[b] = h ? atomicAdd(&bincur[b], h) : 0;
    }
    __syncthreads();
    for (int e = e0 + tid; e < e1; e += 256) {
        int c = col[e];
        int b = c >> 8;
        int pos = atomicAdd(&lofs[b], 1);
        pairs[lbase[b] + pos] = ((unsigned)(c & 255) << 17) | (unsigned)row[e];
    }
}

// pass C: one block per bin; scatter rows into CSR order within the bin's
// 32KB window (single XCD => line assembly). LDS indptr slice + LDS cursors.
__global__ __launch_bounds__(256) void k_csr(const unsigned* __restrict__ pairs,
                                             const int* __restrict__ indptr,
                                             int* __restrict__ rows_s) {
    __shared__ int lptr[257];
    __shared__ int lcnt[256];
    int tid = threadIdx.x;
    int n0 = blockIdx.x << 8;
    int nb = N_NODES - n0; if (nb > 256) nb = 256;
    for (int i = tid; i <= nb; i += 256) lptr[i] = indptr[n0 + i];
    if (tid < nb) lcnt[tid] = 0;
    __syncthreads();
    int s0 = lptr[0], s1 = lptr[nb];
    for (int s = s0 + tid; s < s1; s += 256) {
        unsigned p = pairs[s];
        int cl = p >> 17;
        int r  = p & 0x1FFFF;
        int dst = lptr[cl] + atomicAdd(&lcnt[cl], 1);
        rows_s[dst] = r;
    }
}

// ---------------- encoder: x = relu(X@W0+b0)@W1+b1 ----------------

__global__ __launch_bounds__(256) void k_enc(const float* __restrict__ X,
                                             const float* __restrict__ W0, const float* __restrict__ b0,
                                             const float* __restrict__ W1, const float* __restrict__ b1,
                                             float* __restrict__ xo) {
    __shared__ float W0s[DIN * DIM];   // 8 KB
    __shared__ float W1s[DIM * DIM];   // 64 KB
    __shared__ float b0s[DIM], b1s[DIM];
    __shared__ float Xs[16 * DIN];
    __shared__ float ts[16 * DIM];     // 8 KB
    int tid = threadIdx.x;
    for (int i = tid; i < DIN * DIM / 4; i += 256) ((float4*)W0s)[i] = ((const float4*)W0)[i];
    for (int i = tid; i < DIM * DIM / 4; i += 256) ((float4*)W1s)[i] = ((const float4*)W1)[i];
    if (tid < DIM) { b0s[tid] = b0[tid]; b1s[tid] = b1[tid]; }
    int lane = tid & 63, wv = tid >> 6;
    int j2 = lane * 2;
    int na = wv * 4;
    const int ngroups = N_NODES / 16;
    for (int g = blockIdx.x; g < ngroups; g += gridDim.x) {
        int n0 = g * 16;
        __syncthreads();
        if (tid < 64) ((float4*)Xs)[tid] = ((const float4*)(X + (size_t)n0 * DIN))[tid];
        __syncthreads();
        float2 a[4];
        #pragma unroll
        for (int nd = 0; nd < 4; nd++) a[nd] = make_float2(b0s[j2], b0s[j2 + 1]);
        for (int i = 0; i < DIN; i += 4) {
            float4 xv[4];
            #pragma unroll
            for (int nd = 0; nd < 4; nd++) xv[nd] = *(const float4*)&Xs[(na + nd) * DIN + i];
            #pragma unroll
            for (int k = 0; k < 4; k++) {
                float2 w = *(const float2*)&W0s[(i + k) * DIM + j2];
                #pragma unroll
                for (int nd = 0; nd < 4; nd++) {
                    float f = ((const float*)&xv[nd])[k];
                    a[nd].x += f * w.x; a[nd].y += f * w.y;
                }
            }
        }
        #pragma unroll
        for (int nd = 0; nd < 4; nd++) {
            ts[(na + nd) * DIM + j2]     = fmaxf(a[nd].x, 0.f);
            ts[(na + nd) * DIM + j2 + 1] = fmaxf(a[nd].y, 0.f);
        }
        __syncthreads();
        float2 c[4];
        #pragma unroll
        for (int nd = 0; nd < 4; nd++) c[nd] = make_float2(b1s[j2], b1s[j2 + 1]);
        for (int i = 0; i < DIM; i += 4) {
            float4 tv[4];
            #pragma unroll
            for (int nd = 0; nd < 4; nd++) tv[nd] = *(const float4*)&ts[(na + nd) * DIM + i];
            #pragma unroll
            for (int k = 0; k < 4; k++) {
                float2 w = *(const float2*)&W1s[(i + k) * DIM + j2];
                #pragma unroll
                for (int nd = 0; nd < 4; nd++) {
                    float f = ((const float*)&tv[nd])[k];
                    c[nd].x += f * w.x; c[nd].y += f * w.y;
                }
            }
        }
        #pragma unroll
        for (int nd = 0; nd < 4; nd++)
            *(float2*)&xo[(size_t)(n0 + na + nd) * DIM + j2] = c[nd];
    }
}

// ---------------- conv GEMM: hs_bf16 = pack_bf16((x @ W_conv) * dinv[node]) ----------------

__global__ __launch_bounds__(256) void k_conv(const float* __restrict__ xi,
                                              const float* __restrict__ W,
                                              const float* __restrict__ dinv,
                                              unsigned* __restrict__ hs) {
    __shared__ float Ws[DIM * DIM];    // 64 KB
    __shared__ float xs[16 * DIM];     // 8 KB
    int tid = threadIdx.x;
    for (int i = tid; i < DIM * DIM / 4; i += 256) ((float4*)Ws)[i] = ((const float4*)W)[i];
    int lane = tid & 63, wv = tid >> 6;
    int j2 = lane * 2;
    int na = wv * 4;
    const int ngroups = N_NODES / 16;
    for (int g = blockIdx.x; g < ngroups; g += gridDim.x) {
        int n0 = g * 16;
        __syncthreads();
        for (int i = tid; i < 16 * DIM / 4; i += 256)
            ((float4*)xs)[i] = ((const float4*)(xi + (size_t)n0 * DIM))[i];
        __syncthreads();
        float2 acc[4] = {{0,0},{0,0},{0,0},{0,0}};
        for (int i = 0; i < DIM; i += 4) {
            float4 xv[4];
            #pragma unroll
            for (int nd = 0; nd < 4; nd++) xv[nd] = *(const float4*)&xs[(na + nd) * DIM + i];
            #pragma unroll
            for (int k = 0; k < 4; k++) {
                float2 w = *(const float2*)&Ws[(i + k) * DIM + j2];
                #pragma unroll
                for (int nd = 0; nd < 4; nd++) {
                    float f = ((const float*)&xv[nd])[k];
                    acc[nd].x += f * w.x; acc[nd].y += f * w.y;
                }
            }
        }
        #pragma unroll
        for (int nd = 0; nd < 4; nd++) {
            float d = dinv[n0 + na + nd];
            unsigned pack = f2bf(acc[nd].x * d) | (f2bf(acc[nd].y * d) << 16);
            hs[(size_t)(n0 + na + nd) * 64 + lane] = pack;
        }
    }
}

// ---------------- fused gather + residual + bias + LayerNorm ----------------
// one wave per node; lane holds cols (2l, 2l+1); hs is packed bf16x2; 8-deep MLP

__global__ __launch_bounds__(256) void k_agg_ln(const unsigned* __restrict__ hs, float* __restrict__ x,
                                                const float* __restrict__ dinv,
                                                const int* __restrict__ indptr,
                                                const int* __restrict__ rows_s,
                                                const float* __restrict__ bconv,
                                                const float* __restrict__ g_, const float* __restrict__ b_) {
    int v = (blockIdx.x * blockDim.x + threadIdx.x) >> 6;
    int lane = threadIdx.x & 63;
    if (v >= N_NODES) return;
    int beg = indptr[v], end = indptr[v + 1];
    float accx, accy;
    { unsigned u = hs[(size_t)v * 64 + lane]; accx = bf_lo(u); accy = bf_hi(u); }  // self loop
    for (int base = beg; base < end; base += 64) {
        int m = end - base; if (m > 64) m = 64;
        int r0 = rows_s[base + (lane < m ? lane : m - 1)];
        int k = 0;
        for (; k + 8 <= m; k += 8) {
            int r[8];
            #pragma unroll
            for (int q = 0; q < 8; q++) r[q] = __shfl(r0, k + q);
            unsigned u[8];
            #pragma unroll
            for (int q = 0; q < 8; q++) u[q] = hs[(size_t)r[q] * 64 + lane];
            #pragma unroll
            for (int q = 0; q < 8; q++) { accx += bf_lo(u[q]); accy += bf_hi(u[q]); }
        }
        for (; k < m; k++) {
            int r = __shfl(r0, k);
            unsigned A = hs[(size_t)r * 64 + lane];
            accx += bf_lo(A); accy += bf_hi(A);
        }
    }
    float dv = dinv[v];
    float2 xv = ((const float2*)x)[(size_t)v * 64 + lane];
    float2 bc = ((const float2*)bconv)[lane];
    float yx = xv.x + dv * accx + bc.x;
    float yy = xv.y + dv * accy + bc.y;
    float s = yx + yy, s2 = yx * yx + yy * yy;
    for (int off = 32; off > 0; off >>= 1) {
        s += __shfl_down(s, off);
        s2 += __shfl_down(s2, off);
    }
    float mu = __shfl(s, 0) * (1.f / 128.f);
    float ms = __shfl(s2, 0) * (1.f / 128.f);
    float rstd = rsqrtf(ms - mu * mu + LN_EPS);
    float2 gg = ((const float2*)g_)[lane];
    float2 bb = ((const float2*)b_)[lane];
    float ox = (yx - mu) * rstd * gg.x + bb.x;
    float oy = (yy - mu) * rstd * gg.y + bb.y;
    ((float2*)x)[(size_t)v * 64 + lane] = make_float2(ox, oy);
}

// ---------------- decoder: out = relu(x@W0+b0)@W1+b1 ----------------

#define TSD 136   // padded ts stride (floats)

__global__ __launch_bounds__(256) void k_dec(const float* __restrict__ xi,
                                             const float* __restrict__ W0, const float* __restrict__ b0,
                                             const float* __restrict__ W1, const float* __restrict__ b1,
                                             float* __restrict__ out) {
    __shared__ float W0s[DIM * DIM];    // 64 KB
    __shared__ float W1s[DIM * DOUT];   // 8 KB
    __shared__ float b0s[DIM], b1s[DOUT];
    __shared__ float xs[16 * DIM];      // 8 KB
    __shared__ float ts[16 * TSD];
    int tid = threadIdx.x;
    for (int i = tid; i < DIM * DIM / 4; i += 256) ((float4*)W0s)[i] = ((const float4*)W0)[i];
    for (int i = tid; i < DIM * DOUT / 4; i += 256) ((float4*)W1s)[i] = ((const float4*)W1)[i];
    if (tid < DIM) b0s[tid] = b0[tid];
    if (tid < DOUT) b1s[tid] = b1[tid];
    int lane = tid & 63, wv = tid >> 6;
    int j2 = lane * 2;
    int na = wv * 4;
    const int ngroups = N_NODES / 16;
    for (int g = blockIdx.x; g < ngroups; g += gridDim.x) {
        int n0 = g * 16;
        __syncthreads();
        for (int i = tid; i < 16 * DIM / 4; i += 256)
            ((float4*)xs)[i] = ((const float4*)(xi + (size_t)n0 * DIM))[i];
        __syncthreads();
        float2 a[4];
        #pragma unroll
        for (int nd = 0; nd < 4; nd++) a[nd] = make_float2(b0s[j2], b0s[j2 + 1]);
        for (int i = 0; i < DIM; i += 4) {
            float4 xv[4];
            #pragma unroll
            for (int nd = 0; nd < 4; nd++) xv[nd] = *(const float4*)&xs[(na + nd) * DIM + i];
            #pragma unroll
            for (int k = 0; k < 4; k++) {
                float2 w = *(const float2*)&W0s[(i + k) * DIM + j2];
                #pragma unroll
                for (int nd = 0; nd < 4; nd++) {
                    float f = ((const float*)&xv[nd])[k];
                    a[nd].x += f * w.x; a[nd].y += f * w.y;
                }
            }
        }
        #pragma unroll
        for (int nd = 0; nd < 4; nd++) {
            ts[(na + nd) * TSD + j2]     = fmaxf(a[nd].x, 0.f);
            ts[(na + nd) * TSD + j2 + 1] = fmaxf(a[nd].y, 0.f);
        }
        __syncthreads();
        {   // layer2: 256 threads = 16 nodes x 16 cols
            int node = tid >> 4, c = tid & 15;
            float acc = b1s[c];
            for (int i = 0; i < DIM; i++)
                acc += ts[node * TSD + i] * W1s[i * DOUT + c];
            out[(size_t)(n0 + node) * DOUT + c] = acc;
        }
    }
}

// ---------------- launch ----------------

extern "C" void kernel_launch(void* const* d_in, const int* in_sizes, int n_in,
                              void* d_out, int out_size, void* d_ws, size_t ws_size,
                              hipStream_t stream) {
    const float* X      = (const float*)d_in[0];
    const float* W_enc0 = (const float*)d_in[1];
    const float* b_enc0 = (const float*)d_in[2];
    const float* W_enc1 = (const float*)d_in[3];
    const float* b_enc1 = (const float*)d_in[4];
    const float* W_conv = (const float*)d_in[5];
    const float* b_conv = (const float*)d_in[6];
    const float* ln_g   = (const float*)d_in[7];
    const float* ln_b   = (const float*)d_in[8];
    const float* W_dec0 = (const float*)d_in[9];
    const float* b_dec0 = (const float*)d_in[10];
    const float* W_dec1 = (const float*)d_in[11];
    const float* b_dec1 = (const float*)d_in[12];
    const int*   erow   = (const int*)d_in[13];         // edge_index[0] = sources
    const int*   ecol   = erow + NEDGE;                 // edge_index[1] = targets
    float* out = (float*)d_out;

    float*    x      = (float*)d_ws;                            // N*128 f32
    unsigned* hs     = (unsigned*)(x + (size_t)N_NODES * DIM);  // N*64 u32 (bf16x2)
    float*    dinv   = (float*)(hs + (size_t)N_NODES * 64);     // N f32
    int*      cnt    = (int*)(dinv + N_NODES);                  // N int
    int*      indptr = cnt + N_NODES;                           // N+1 int
    int*      bsum   = indptr + N_NODES + 8;                    // NBLK
    int*      boff   = bsum + NBLK + 8;                         // NBLK
    int*      bincur = boff + NBLK + 8;                         // NBINS
    int*      rows_s = bincur + NBINS + 8;                      // E int
    unsigned* pairs  = hs;   // overlay: build finishes before k_conv writes hs

    // CSR build (per launch; d_ws is re-poisoned before every call)
    k_zero   <<<NBLK, 256, 0, stream>>>(cnt);
    k_count  <<<(NEDGE + 255) / 256, 256, 0, stream>>>(ecol, cnt);
    k_bsum   <<<NBLK, 256, 0, stream>>>(cnt, bsum, dinv);
    k_bscan  <<<1, 512, 0, stream>>>(bsum, boff);
    k_indptr <<<NBLK, 256, 0, stream>>>(cnt, boff, indptr, bincur);
    k_binpass<<<NPB, 256, 0, stream>>>(erow, ecol, bincur, pairs);
    k_csr    <<<NBINS, 256, 0, stream>>>(pairs, indptr, rows_s);

    k_enc<<<512, 256, 0, stream>>>(X, W_enc0, b_enc0, W_enc1, b_enc1, x);

    for (int s = 0; s < 3; s++) {   // msg_steps = 3 (fixed scalar input)
        k_conv<<<512, 256, 0, stream>>>(x, W_conv, dinv, hs);
        k_agg_ln<<<N_NODES / 4, 256, 0, stream>>>(hs, x, dinv, indptr, rows_s, b_conv, ln_g, ln_b);
    }

    k_dec<<<512, 256, 0, stream>>>(x, W_dec0, b_dec0, W_dec1, b_dec1, out);
}

// Round 4
// 771.233 us; speedup vs baseline: 2.4897x; 1.4457x over previous
//
#include <hip/hip_runtime.h>

#define N_NODES 100000
#define NEDGE   3200000
#define DIN     16
#define DIM     128
#define DOUT    16
#define LN_EPS  1e-5f
#define NBLK    391          // ceil(100000/256) scan blocks
#define NBINS   391          // 256-target bins: bin = c >> 8
#define CHUNK   16384        // edges per pass-B block
#define NPB     196          // ceil(NEDGE / CHUNK)
#define XS_STRIDE 136        // LDS bf16 row stride: 272B, 16B-aligned, 2-way-bank free
#define GGRID   1024         // GEMM grid

typedef __attribute__((ext_vector_type(8))) __bf16 bfrag_t;
typedef __attribute__((ext_vector_type(4))) float facc_t;

static __device__ __forceinline__ facc_t mfma16(bfrag_t a, bfrag_t b, facc_t c) {
    return __builtin_amdgcn_mfma_f32_16x16x32_bf16(a, b, c, 0, 0, 0);
}

// ---- bf16 helpers (RNE pack, cheap unpack) ----
static __device__ __forceinline__ unsigned f2bf(float f) {
    unsigned u = __float_as_uint(f);
    return (u + 0x7fffu + ((u >> 16) & 1u)) >> 16;
}
static __device__ __forceinline__ float bf_lo(unsigned u) { return __uint_as_float(u << 16); }
static __device__ __forceinline__ float bf_hi(unsigned u) { return __uint_as_float(u & 0xFFFF0000u); }

// ---------------- CSR build ----------------

__global__ __launch_bounds__(256) void k_zero(int* __restrict__ cnt) {
    int i = blockIdx.x * 256 + threadIdx.x;
    if (i < N_NODES) cnt[i] = 0;
}

__global__ __launch_bounds__(256) void k_count(const int* __restrict__ col, int* __restrict__ cnt) {
    int i = blockIdx.x * 256 + threadIdx.x;
    if (i < NEDGE) atomicAdd(&cnt[col[i]], 1);
}

__global__ __launch_bounds__(256) void k_bsum(const int* __restrict__ cnt, int* __restrict__ bsum,
                                              float* __restrict__ dinv) {
    int i = blockIdx.x * 256 + threadIdx.x;
    int v = 0;
    if (i < N_NODES) {
        v = cnt[i];
        dinv[i] = rsqrtf((float)(v + 1));   // +1 self loop, always > 0
    }
    int s = v;
    for (int off = 32; off > 0; off >>= 1) s += __shfl_down(s, off);
    __shared__ int ws4[4];
    if ((threadIdx.x & 63) == 0) ws4[threadIdx.x >> 6] = s;
    __syncthreads();
    if (threadIdx.x == 0) bsum[blockIdx.x] = ws4[0] + ws4[1] + ws4[2] + ws4[3];
}

__global__ __launch_bounds__(512) void k_bscan(const int* __restrict__ bsum, int* __restrict__ boff) {
    __shared__ int sh[512];
    int t = threadIdx.x;
    int v = (t < NBLK) ? bsum[t] : 0;
    sh[t] = v;
    __syncthreads();
    for (int off = 1; off < 512; off <<= 1) {
        int a = (t >= off) ? sh[t - off] : 0;
        __syncthreads();
        sh[t] += a;
        __syncthreads();
    }
    if (t < NBLK) boff[t] = sh[t] - v;
}

__global__ __launch_bounds__(256) void k_indptr(int* __restrict__ cnt, const int* __restrict__ boff,
                                                int* __restrict__ indptr, int* __restrict__ bincur) {
    int i = blockIdx.x * 256 + threadIdx.x;
    int lane = threadIdx.x & 63, w = threadIdx.x >> 6;
    int v = (i < N_NODES) ? cnt[i] : 0;
    int s = v;
    for (int off = 1; off < 64; off <<= 1) {
        int t = __shfl_up(s, off);
        if (lane >= off) s += t;
    }
    __shared__ int wsum[4];
    if (lane == 63) wsum[w] = s;
    __syncthreads();
    int add = boff[blockIdx.x];
    for (int k = 0; k < w; k++) add += wsum[k];
    int excl = add + s - v;
    if (i < N_NODES) {
        indptr[i] = excl;
        cnt[i] = 0;
        if ((i & 255) == 0) bincur[i >> 8] = excl;
        if (i == N_NODES - 1) indptr[N_NODES] = excl + v;
    }
}

__global__ __launch_bounds__(256) void k_binpass(const int* __restrict__ row, const int* __restrict__ col,
                                                 int* __restrict__ bincur, unsigned* __restrict__ pairs) {
    __shared__ int lhist[NBINS], lbase[NBINS], lofs[NBINS];
    int tid = threadIdx.x;
    for (int b = tid; b < NBINS; b += 256) { lhist[b] = 0; lofs[b] = 0; }
    __syncthreads();
    int e0 = blockIdx.x * CHUNK;
    int e1 = e0 + CHUNK; if (e1 > NEDGE) e1 = NEDGE;
    for (int e = e0 + tid; e < e1; e += 256)
        atomicAdd(&lhist[col[e] >> 8], 1);
    __syncthreads();
    for (int b = tid; b < NBINS; b += 256) {
        int h = lhist[b];
        lbase[b] = h ? atomicAdd(&bincur[b], h) : 0;
    }
    __syncthreads();
    for (int e = e0 + tid; e < e1; e += 256) {
        int c = col[e];
        int b = c >> 8;
        int pos = atomicAdd(&lofs[b], 1);
        pairs[lbase[b] + pos] = ((unsigned)(c & 255) << 17) | (unsigned)row[e];
    }
}

__global__ __launch_bounds__(256) void k_csr(const unsigned* __restrict__ pairs,
                                             const int* __restrict__ indptr,
                                             int* __restrict__ rows_s) {
    __shared__ int lptr[257];
    __shared__ int lcnt[256];
    int tid = threadIdx.x;
    int n0 = blockIdx.x << 8;
    int nb = N_NODES - n0; if (nb > 256) nb = 256;
    for (int i = tid; i <= nb; i += 256) lptr[i] = indptr[n0 + i];
    if (tid < nb) lcnt[tid] = 0;
    __syncthreads();
    int s0 = lptr[0], s1 = lptr[nb];
    for (int s = s0 + tid; s < s1; s += 256) {
        unsigned p = pairs[s];
        int cl = p >> 17;
        int r  = p & 0x1FFFF;
        int dst = lptr[cl] + atomicAdd(&lcnt[cl], 1);
        rows_s[dst] = r;
    }
}

// ---------------- MFMA helpers ----------------
// B-fragment layout for mfma_f32_16x16x32_bf16: lane l holds B[k][n],
// n = (l&15)+col0, k = 32*kc + 8*(l>>4) + j (j=0..7). W row-major [128 x NC] fp32.
template<int NC, int NT>
static __device__ __forceinline__ void load_bfrags(const float* __restrict__ W, int colbase,
                                                   int lane, bfrag_t B[NT][4]) {
    int q = lane >> 4, nn = lane & 15;
    #pragma unroll
    for (int nt = 0; nt < NT; nt++) {
        int col = colbase + 16 * nt + nn;
        #pragma unroll
        for (int kc = 0; kc < 4; kc++) {
            int k0 = 32 * kc + 8 * q;
            bfrag_t f;
            #pragma unroll
            for (int j = 0; j < 8; j++)
                f[j] = (__bf16)W[(size_t)(k0 + j) * NC + col];
            B[nt][kc] = f;
        }
    }
}

// stage 32x128 fp32 rows -> bf16 LDS tile (stride XS_STRIDE)
static __device__ __forceinline__ void stage_tile(const float* __restrict__ src_base,
                                                  short* __restrict__ xs, int tid) {
    int r = tid >> 3, s = tid & 7;
    const float4* src = (const float4*)(src_base + (size_t)r * DIM + 16 * s);
    float4 v0 = src[0], v1 = src[1], v2 = src[2], v3 = src[3];
    uint4 lo, hi;
    lo.x = f2bf(v0.x) | (f2bf(v0.y) << 16);
    lo.y = f2bf(v0.z) | (f2bf(v0.w) << 16);
    lo.z = f2bf(v1.x) | (f2bf(v1.y) << 16);
    lo.w = f2bf(v1.z) | (f2bf(v1.w) << 16);
    hi.x = f2bf(v2.x) | (f2bf(v2.y) << 16);
    hi.y = f2bf(v2.z) | (f2bf(v2.w) << 16);
    hi.z = f2bf(v3.x) | (f2bf(v3.y) << 16);
    hi.w = f2bf(v3.z) | (f2bf(v3.w) << 16);
    *(uint4*)&xs[r * XS_STRIDE + 16 * s] = lo;
    *(uint4*)&xs[r * XS_STRIDE + 16 * s + 8] = hi;
}

// ---------------- encoder (fused): x = relu(X@W0+b0)@W1 + b1 ----------------

__global__ __launch_bounds__(256) void k_encM(const float* __restrict__ X,
                                              const float* __restrict__ W0, const float* __restrict__ b0,
                                              const float* __restrict__ W1, const float* __restrict__ b1,
                                              float* __restrict__ xo) {
    __shared__ short xs[32 * XS_STRIDE];
    __shared__ float W0s[DIN * DIM];   // 8 KB
    __shared__ float b0s[DIM];
    int tid = threadIdx.x, lane = tid & 63, wv = tid >> 6;
    for (int i = tid; i < DIN * DIM / 4; i += 256) ((float4*)W0s)[i] = ((const float4*)W0)[i];
    if (tid < DIM) b0s[tid] = b0[tid];
    bfrag_t B[2][4];
    load_bfrags<DIM, 2>(W1, 32 * wv, lane, B);
    int q = lane >> 4, nn = lane & 15;
    float bias[2] = { b1[32 * wv + nn], b1[32 * wv + 16 + nn] };
    const int ngroups = N_NODES / 32;
    for (int g = blockIdx.x; g < ngroups; g += gridDim.x) {
        int n0 = g * 32;
        __syncthreads();
        {   // stage: t = relu(X@W0+b0), node r, cols 16s..16s+15 -> bf16 LDS
            int r = tid >> 3, s = tid & 7;
            float xr[DIN];
            const float4* xsrc = (const float4*)(X + (size_t)(n0 + r) * DIN);
            #pragma unroll
            for (int i = 0; i < 4; i++) {
                float4 v = xsrc[i];
                xr[4*i] = v.x; xr[4*i+1] = v.y; xr[4*i+2] = v.z; xr[4*i+3] = v.w;
            }
            unsigned pk[8];
            #pragma unroll
            for (int cc = 0; cc < 16; cc += 2) {
                int c0 = 16 * s + cc;
                float a0 = b0s[c0], a1 = b0s[c0 + 1];
                #pragma unroll
                for (int k = 0; k < DIN; k++) {
                    float2 w = *(const float2*)&W0s[k * DIM + c0];
                    a0 += xr[k] * w.x; a1 += xr[k] * w.y;
                }
                pk[cc >> 1] = f2bf(fmaxf(a0, 0.f)) | (f2bf(fmaxf(a1, 0.f)) << 16);
            }
            *(uint4*)&xs[r * XS_STRIDE + 16 * s] = *(uint4*)&pk[0];
            *(uint4*)&xs[r * XS_STRIDE + 16 * s + 8] = *(uint4*)&pk[4];
        }
        __syncthreads();
        facc_t acc[2][2];
        #pragma unroll
        for (int mt = 0; mt < 2; mt++)
            #pragma unroll
            for (int nt = 0; nt < 2; nt++)
                acc[mt][nt] = (facc_t){bias[nt], bias[nt], bias[nt], bias[nt]};
        #pragma unroll
        for (int kc = 0; kc < 4; kc++) {
            bfrag_t a0 = *(const bfrag_t*)&xs[nn * XS_STRIDE + 32 * kc + 8 * q];
            bfrag_t a1 = *(const bfrag_t*)&xs[(16 + nn) * XS_STRIDE + 32 * kc + 8 * q];
            acc[0][0] = mfma16(a0, B[0][kc], acc[0][0]);
            acc[0][1] = mfma16(a0, B[1][kc], acc[0][1]);
            acc[1][0] = mfma16(a1, B[0][kc], acc[1][0]);
            acc[1][1] = mfma16(a1, B[1][kc], acc[1][1]);
        }
        #pragma unroll
        for (int mt = 0; mt < 2; mt++)
            #pragma unroll
            for (int r = 0; r < 4; r++) {
                int node = n0 + 16 * mt + 4 * q + r;
                #pragma unroll
                for (int nt = 0; nt < 2; nt++)
                    xo[(size_t)node * DIM + 32 * wv + 16 * nt + nn] = acc[mt][nt][r];
            }
    }
}

// ---------------- conv: hs_bf16 = (x @ W_conv) * dinv[node] ----------------

__global__ __launch_bounds__(256) void k_convM(const float* __restrict__ xi,
                                               const float* __restrict__ W,
                                               const float* __restrict__ dinv,
                                               unsigned short* __restrict__ hs) {
    __shared__ short xs[32 * XS_STRIDE];
    int tid = threadIdx.x, lane = tid & 63, wv = tid >> 6;
    bfrag_t B[2][4];
    load_bfrags<DIM, 2>(W, 32 * wv, lane, B);
    int q = lane >> 4, nn = lane & 15;
    const int ngroups = N_NODES / 32;
    for (int g = blockIdx.x; g < ngroups; g += gridDim.x) {
        int n0 = g * 32;
        __syncthreads();
        stage_tile(xi + (size_t)n0 * DIM, xs, tid);
        __syncthreads();
        facc_t acc[2][2] = {};
        #pragma unroll
        for (int kc = 0; kc < 4; kc++) {
            bfrag_t a0 = *(const bfrag_t*)&xs[nn * XS_STRIDE + 32 * kc + 8 * q];
            bfrag_t a1 = *(const bfrag_t*)&xs[(16 + nn) * XS_STRIDE + 32 * kc + 8 * q];
            acc[0][0] = mfma16(a0, B[0][kc], acc[0][0]);
            acc[0][1] = mfma16(a0, B[1][kc], acc[0][1]);
            acc[1][0] = mfma16(a1, B[0][kc], acc[1][0]);
            acc[1][1] = mfma16(a1, B[1][kc], acc[1][1]);
        }
        #pragma unroll
        for (int mt = 0; mt < 2; mt++)
            #pragma unroll
            for (int r = 0; r < 4; r++) {
                int node = n0 + 16 * mt + 4 * q + r;
                float d = dinv[node];
                #pragma unroll
                for (int nt = 0; nt < 2; nt++)
                    hs[(size_t)node * DIM + 32 * wv + 16 * nt + nn] =
                        (unsigned short)f2bf(acc[mt][nt][r] * d);
            }
    }
}

// ---------------- fused gather + residual + bias + LayerNorm (unchanged) ----------------

__global__ __launch_bounds__(256) void k_agg_ln(const unsigned* __restrict__ hs, float* __restrict__ x,
                                                const float* __restrict__ dinv,
                                                const int* __restrict__ indptr,
                                                const int* __restrict__ rows_s,
                                                const float* __restrict__ bconv,
                                                const float* __restrict__ g_, const float* __restrict__ b_) {
    int v = (blockIdx.x * blockDim.x + threadIdx.x) >> 6;
    int lane = threadIdx.x & 63;
    if (v >= N_NODES) return;
    int beg = indptr[v], end = indptr[v + 1];
    float accx, accy;
    { unsigned u = hs[(size_t)v * 64 + lane]; accx = bf_lo(u); accy = bf_hi(u); }  // self loop
    for (int base = beg; base < end; base += 64) {
        int m = end - base; if (m > 64) m = 64;
        int r0 = rows_s[base + (lane < m ? lane : m - 1)];
        int k = 0;
        for (; k + 8 <= m; k += 8) {
            int r[8];
            #pragma unroll
            for (int qq = 0; qq < 8; qq++) r[qq] = __shfl(r0, k + qq);
            unsigned u[8];
            #pragma unroll
            for (int qq = 0; qq < 8; qq++) u[qq] = hs[(size_t)r[qq] * 64 + lane];
            #pragma unroll
            for (int qq = 0; qq < 8; qq++) { accx += bf_lo(u[qq]); accy += bf_hi(u[qq]); }
        }
        for (; k < m; k++) {
            int r = __shfl(r0, k);
            unsigned A = hs[(size_t)r * 64 + lane];
            accx += bf_lo(A); accy += bf_hi(A);
        }
    }
    float dv = dinv[v];
    float2 xv = ((const float2*)x)[(size_t)v * 64 + lane];
    float2 bc = ((const float2*)bconv)[lane];
    float yx = xv.x + dv * accx + bc.x;
    float yy = xv.y + dv * accy + bc.y;
    float s = yx + yy, s2 = yx * yx + yy * yy;
    for (int off = 32; off > 0; off >>= 1) {
        s += __shfl_down(s, off);
        s2 += __shfl_down(s2, off);
    }
    float mu = __shfl(s, 0) * (1.f / 128.f);
    float ms = __shfl(s2, 0) * (1.f / 128.f);
    float rstd = rsqrtf(ms - mu * mu + LN_EPS);
    float2 gg = ((const float2*)g_)[lane];
    float2 bb = ((const float2*)b_)[lane];
    float ox = (yx - mu) * rstd * gg.x + bb.x;
    float oy = (yy - mu) * rstd * gg.y + bb.y;
    ((float2*)x)[(size_t)v * 64 + lane] = make_float2(ox, oy);
}

// ---------------- decoder (fused): out = relu(x@W0+b0)@W1 + b1 ----------------

__global__ __launch_bounds__(256) void k_decM(const float* __restrict__ xi,
                                              const float* __restrict__ W0, const float* __restrict__ b0f,
                                              const float* __restrict__ W1, const float* __restrict__ b1f,
                                              float* __restrict__ out) {
    __shared__ short xs[32 * XS_STRIDE];
    int tid = threadIdx.x, lane = tid & 63, wv = tid >> 6;
    bfrag_t B0[2][4];
    load_bfrags<DIM, 2>(W0, 32 * wv, lane, B0);
    int q = lane >> 4, nn = lane & 15;
    bfrag_t B1[4];
    #pragma unroll
    for (int kc = 0; kc < 4; kc++) {
        int k0 = 32 * kc + 8 * q;
        bfrag_t f;
        #pragma unroll
        for (int j = 0; j < 8; j++)
            f[j] = (__bf16)W1[(size_t)(k0 + j) * DOUT + nn];
        B1[kc] = f;
    }
    float bias0[2] = { b0f[32 * wv + nn], b0f[32 * wv + 16 + nn] };
    float bias1 = b1f[nn];
    const int ngroups = N_NODES / 32;
    for (int g = blockIdx.x; g < ngroups; g += gridDim.x) {
        int n0 = g * 32;
        __syncthreads();
        stage_tile(xi + (size_t)n0 * DIM, xs, tid);
        __syncthreads();
        facc_t acc[2][2];
        #pragma unroll
        for (int mt = 0; mt < 2; mt++)
            #pragma unroll
            for (int nt = 0; nt < 2; nt++)
                acc[mt][nt] = (facc_t){bias0[nt], bias0[nt], bias0[nt], bias0[nt]};
        #pragma unroll
        for (int kc = 0; kc < 4; kc++) {
            bfrag_t a0 = *(const bfrag_t*)&xs[nn * XS_STRIDE + 32 * kc + 8 * q];
            bfrag_t a1 = *(const bfrag_t*)&xs[(16 + nn) * XS_STRIDE + 32 * kc + 8 * q];
            acc[0][0] = mfma16(a0, B0[0][kc], acc[0][0]);
            acc[0][1] = mfma16(a0, B0[1][kc], acc[0][1]);
            acc[1][0] = mfma16(a1, B0[0][kc], acc[1][0]);
            acc[1][1] = mfma16(a1, B0[1][kc], acc[1][1]);
        }
        __syncthreads();   // all A-reads of x-tile done; xs can be overwritten
        // t2 = relu(acc) -> xs as bf16 (row = local node, col = t2 feature = K of layer 2)
        #pragma unroll
        for (int mt = 0; mt < 2; mt++)
            #pragma unroll
            for (int nt = 0; nt < 2; nt++)
                #pragma unroll
                for (int r = 0; r < 4; r++) {
                    int nl = 16 * mt + 4 * q + r;
                    int col = 32 * wv + 16 * nt + nn;
                    xs[nl * XS_STRIDE + col] = (short)f2bf(fmaxf(acc[mt][nt][r], 0.f));
                }
        __syncthreads();
        if (wv < 2) {   // waves 0,1: t2[32x128] @ W1[128x16]
            facc_t acc2 = (facc_t){bias1, bias1, bias1, bias1};
            #pragma unroll
            for (int kc = 0; kc < 4; kc++) {
                bfrag_t a = *(const bfrag_t*)&xs[(16 * wv + nn) * XS_STRIDE + 32 * kc + 8 * q];
                acc2 = mfma16(a, B1[kc], acc2);
            }
            #pragma unroll
            for (int r = 0; r < 4; r++) {
                int node = n0 + 16 * wv + 4 * q + r;
                out[(size_t)node * DOUT + nn] = acc2[r];
            }
        }
    }
}

// ---------------- launch ----------------

extern "C" void kernel_launch(void* const* d_in, const int* in_sizes, int n_in,
                              void* d_out, int out_size, void* d_ws, size_t ws_size,
                              hipStream_t stream) {
    const float* X      = (const float*)d_in[0];
    const float* W_enc0 = (const float*)d_in[1];
    const float* b_enc0 = (const float*)d_in[2];
    const float* W_enc1 = (const float*)d_in[3];
    const float* b_enc1 = (const float*)d_in[4];
    const float* W_conv = (const float*)d_in[5];
    const float* b_conv = (const float*)d_in[6];
    const float* ln_g   = (const float*)d_in[7];
    const float* ln_b   = (const float*)d_in[8];
    const float* W_dec0 = (const float*)d_in[9];
    const float* b_dec0 = (const float*)d_in[10];
    const float* W_dec1 = (const float*)d_in[11];
    const float* b_dec1 = (const float*)d_in[12];
    const int*   erow   = (const int*)d_in[13];         // edge_index[0] = sources
    const int*   ecol   = erow + NEDGE;                 // edge_index[1] = targets
    float* out = (float*)d_out;

    float*          x      = (float*)d_ws;                            // N*128 f32
    unsigned short* hs     = (unsigned short*)(x + (size_t)N_NODES * DIM);  // N*128 bf16
    float*          dinv   = (float*)(hs + (size_t)N_NODES * DIM);    // N f32
    int*            cnt    = (int*)(dinv + N_NODES);                  // N int
    int*            indptr = cnt + N_NODES;                           // N+1 int
    int*            bsum   = indptr + N_NODES + 8;                    // NBLK
    int*            boff   = bsum + NBLK + 8;                         // NBLK
    int*            bincur = boff + NBLK + 8;                         // NBINS
    int*            rows_s = bincur + NBINS + 8;                      // E int
    unsigned*       pairs  = (unsigned*)hs;   // overlay: build finishes before conv writes hs

    // CSR build (per launch; d_ws is re-poisoned before every call)
    k_zero   <<<NBLK, 256, 0, stream>>>(cnt);
    k_count  <<<(NEDGE + 255) / 256, 256, 0, stream>>>(ecol, cnt);
    k_bsum   <<<NBLK, 256, 0, stream>>>(cnt, bsum, dinv);
    k_bscan  <<<1, 512, 0, stream>>>(bsum, boff);
    k_indptr <<<NBLK, 256, 0, stream>>>(cnt, boff, indptr, bincur);
    k_binpass<<<NPB, 256, 0, stream>>>(erow, ecol, bincur, pairs);
    k_csr    <<<NBINS, 256, 0, stream>>>(pairs, indptr, rows_s);

    k_encM<<<GGRID, 256, 0, stream>>>(X, W_enc0, b_enc0, W_enc1, b_enc1, x);

    for (int s = 0; s < 3; s++) {   // msg_steps = 3 (fixed scalar input)
        k_convM<<<GGRID, 256, 0, stream>>>(x, W_conv, dinv, hs);
        k_agg_ln<<<N_NODES / 4, 256, 0, stream>>>((const unsigned*)hs, x, dinv, indptr, rows_s,
                                                  b_conv, ln_g, ln_b);
    }

    k_decM<<<GGRID, 256, 0, stream>>>(x, W_dec0, b_dec0, W_dec1, b_dec1, out);
}

// Round 5
// 633.498 us; speedup vs baseline: 3.0311x; 1.2174x over previous
//
#include <hip/hip_runtime.h>

#define N_NODES 100000
#define NEDGE   3200000
#define DIN     16
#define DIM     128
#define DOUT    16
#define LN_EPS  1e-5f
#define NBINS   391          // 256-target bins: bin = c >> 8
#define CHUNK   16384        // edges per chunk block
#define NPB     196          // ceil(NEDGE / CHUNK)
#define XS_STRIDE 136        // LDS bf16 row stride: 272B, 16B-aligned, 2-way-bank free
#define GGRID   1024         // GEMM grid

typedef __attribute__((ext_vector_type(8))) __bf16 bfrag_t;
typedef __attribute__((ext_vector_type(4))) float facc_t;

static __device__ __forceinline__ facc_t mfma16(bfrag_t a, bfrag_t b, facc_t c) {
    return __builtin_amdgcn_mfma_f32_16x16x32_bf16(a, b, c, 0, 0, 0);
}

// ---- bf16 helpers (RNE pack, cheap unpack) ----
static __device__ __forceinline__ unsigned f2bf(float f) {
    unsigned u = __float_as_uint(f);
    return (u + 0x7fffu + ((u >> 16) & 1u)) >> 16;
}
static __device__ __forceinline__ float bf_lo(unsigned u) { return __uint_as_float(u << 16); }
static __device__ __forceinline__ float bf_hi(unsigned u) { return __uint_as_float(u & 0xFFFF0000u); }

// ---------------- CSR build (no global per-node atomics) ----------------

__global__ __launch_bounds__(512) void k_zb(int* __restrict__ binsize) {
    if (threadIdx.x < NBINS) binsize[threadIdx.x] = 0;
}

// per-chunk LDS bin histogram -> 76k global atomics total (vs 3.2M)
__global__ __launch_bounds__(256) void k_hist(const int* __restrict__ col, int* __restrict__ binsize) {
    __shared__ int lh[NBINS];
    int tid = threadIdx.x;
    for (int b = tid; b < NBINS; b += 256) lh[b] = 0;
    __syncthreads();
    int e0 = blockIdx.x * CHUNK;
    int e1 = e0 + CHUNK; if (e1 > NEDGE) e1 = NEDGE;
    for (int e = e0 + tid; e < e1; e += 256)
        atomicAdd(&lh[col[e] >> 8], 1);
    __syncthreads();
    for (int b = tid; b < NBINS; b += 256)
        if (lh[b]) atomicAdd(&binsize[b], lh[b]);
}

// single block: exclusive scan of 391 bin sizes -> binbase (+sentinel), bincur
__global__ __launch_bounds__(512) void k_scanb(const int* __restrict__ binsize,
                                               int* __restrict__ binbase, int* __restrict__ bincur) {
    __shared__ int sh[512];
    int t = threadIdx.x;
    int v = (t < NBINS) ? binsize[t] : 0;
    sh[t] = v;
    __syncthreads();
    for (int off = 1; off < 512; off <<= 1) {
        int a = (t >= off) ? sh[t - off] : 0;
        __syncthreads();
        sh[t] += a;
        __syncthreads();
    }
    if (t < NBINS) {
        int e = sh[t] - v;
        binbase[t] = e;
        bincur[t] = e;
    }
    if (t == 0) binbase[NBINS] = NEDGE;
}

// pass B: bin edges into per-bin regions as packed pairs; per-chunk LDS histogram
// + one global cursor bump per (block,bin) => contiguous per-block ranges => line assembly.
__global__ __launch_bounds__(256) void k_binpass(const int* __restrict__ row, const int* __restrict__ col,
                                                 int* __restrict__ bincur, unsigned* __restrict__ pairs) {
    __shared__ int lhist[NBINS], lbase[NBINS], lofs[NBINS];
    int tid = threadIdx.x;
    for (int b = tid; b < NBINS; b += 256) { lhist[b] = 0; lofs[b] = 0; }
    __syncthreads();
    int e0 = blockIdx.x * CHUNK;
    int e1 = e0 + CHUNK; if (e1 > NEDGE) e1 = NEDGE;
    for (int e = e0 + tid; e < e1; e += 256)
        atomicAdd(&lhist[col[e] >> 8], 1);
    __syncthreads();
    for (int b = tid; b < NBINS; b += 256) {
        int h = lhist[b];
        lbase[b] = h ? atomicAdd(&bincur[b], h) : 0;
    }
    __syncthreads();
    for (int e = e0 + tid; e < e1; e += 256) {
        int c = col[e];
        int b = c >> 8;
        int pos = atomicAdd(&lofs[b], 1);
        pairs[lbase[b] + pos] = ((unsigned)(c & 255) << 17) | (unsigned)row[e];
    }
}

// pass C: one block per bin. Count 256 targets in LDS, block-scan -> indptr + dinv,
// then scatter rows into the bin's CSR window (single-XCD => line assembly).
__global__ __launch_bounds__(256) void k_csr2(const unsigned* __restrict__ pairs,
                                              const int* __restrict__ binbase,
                                              int* __restrict__ indptr, float* __restrict__ dinv,
                                              int* __restrict__ rows_s) {
    __shared__ int lcnt[256], lptr[256], lofs[256];
    __shared__ int wsum[4];
    int tid = threadIdx.x;
    int b = blockIdx.x;
    int n0 = b << 8;
    int base = binbase[b], end = binbase[b + 1];
    lcnt[tid] = 0; lofs[tid] = 0;
    __syncthreads();
    for (int s = base + tid; s < end; s += 256)
        atomicAdd(&lcnt[pairs[s] >> 17], 1);
    __syncthreads();
    int v = lcnt[tid];
    int lane = tid & 63, w = tid >> 6;
    int s = v;
    for (int off = 1; off < 64; off <<= 1) {
        int t = __shfl_up(s, off);
        if (lane >= off) s += t;
    }
    if (lane == 63) wsum[w] = s;
    __syncthreads();
    int add = 0;
    for (int k = 0; k < w; k++) add += wsum[k];
    int excl = add + s - v;
    lptr[tid] = excl;
    int node = n0 + tid;
    if (node < N_NODES) {
        indptr[node] = base + excl;
        dinv[node] = rsqrtf((float)(v + 1));   // +1 self loop
    }
    if (b == NBINS - 1 && tid == 0) indptr[N_NODES] = NEDGE;
    __syncthreads();
    for (int s2 = base + tid; s2 < end; s2 += 256) {
        unsigned p = pairs[s2];
        int cl = p >> 17;
        int r  = p & 0x1FFFF;
        int dst = base + lptr[cl] + atomicAdd(&lofs[cl], 1);
        rows_s[dst] = r;
    }
}

// ---------------- MFMA helpers ----------------
// B-fragment layout for mfma_f32_16x16x32_bf16: lane l holds B[k][n],
// n = (l&15)+col0, k = 32*kc + 8*(l>>4) + j (j=0..7). W row-major [128 x NC] fp32.
template<int NC, int NT>
static __device__ __forceinline__ void load_bfrags(const float* __restrict__ W, int colbase,
                                                   int lane, bfrag_t B[NT][4]) {
    int q = lane >> 4, nn = lane & 15;
    #pragma unroll
    for (int nt = 0; nt < NT; nt++) {
        int col = colbase + 16 * nt + nn;
        #pragma unroll
        for (int kc = 0; kc < 4; kc++) {
            int k0 = 32 * kc + 8 * q;
            bfrag_t f;
            #pragma unroll
            for (int j = 0; j < 8; j++)
                f[j] = (__bf16)W[(size_t)(k0 + j) * NC + col];
            B[nt][kc] = f;
        }
    }
}

// stage 32x128 fp32 rows -> bf16 LDS tile (stride XS_STRIDE)
static __device__ __forceinline__ void stage_tile(const float* __restrict__ src_base,
                                                  short* __restrict__ xs, int tid) {
    int r = tid >> 3, s = tid & 7;
    const float4* src = (const float4*)(src_base + (size_t)r * DIM + 16 * s);
    float4 v0 = src[0], v1 = src[1], v2 = src[2], v3 = src[3];
    uint4 lo, hi;
    lo.x = f2bf(v0.x) | (f2bf(v0.y) << 16);
    lo.y = f2bf(v0.z) | (f2bf(v0.w) << 16);
    lo.z = f2bf(v1.x) | (f2bf(v1.y) << 16);
    lo.w = f2bf(v1.z) | (f2bf(v1.w) << 16);
    hi.x = f2bf(v2.x) | (f2bf(v2.y) << 16);
    hi.y = f2bf(v2.z) | (f2bf(v2.w) << 16);
    hi.z = f2bf(v3.x) | (f2bf(v3.y) << 16);
    hi.w = f2bf(v3.z) | (f2bf(v3.w) << 16);
    *(uint4*)&xs[r * XS_STRIDE + 16 * s] = lo;
    *(uint4*)&xs[r * XS_STRIDE + 16 * s + 8] = hi;
}

// ---------------- encoder (fused): x = relu(X@W0+b0)@W1 + b1 ----------------

__global__ __launch_bounds__(256) void k_encM(const float* __restrict__ X,
                                              const float* __restrict__ W0, const float* __restrict__ b0,
                                              const float* __restrict__ W1, const float* __restrict__ b1,
                                              float* __restrict__ xo) {
    __shared__ short xs[32 * XS_STRIDE];
    __shared__ float W0s[DIN * DIM];   // 8 KB
    __shared__ float b0s[DIM];
    int tid = threadIdx.x, lane = tid & 63, wv = tid >> 6;
    for (int i = tid; i < DIN * DIM / 4; i += 256) ((float4*)W0s)[i] = ((const float4*)W0)[i];
    if (tid < DIM) b0s[tid] = b0[tid];
    bfrag_t B[2][4];
    load_bfrags<DIM, 2>(W1, 32 * wv, lane, B);
    int q = lane >> 4, nn = lane & 15;
    float bias[2] = { b1[32 * wv + nn], b1[32 * wv + 16 + nn] };
    const int ngroups = N_NODES / 32;
    for (int g = blockIdx.x; g < ngroups; g += gridDim.x) {
        int n0 = g * 32;
        __syncthreads();
        {   // stage: t = relu(X@W0+b0), node r, cols 16s..16s+15 -> bf16 LDS
            int r = tid >> 3, s = tid & 7;
            float xr[DIN];
            const float4* xsrc = (const float4*)(X + (size_t)(n0 + r) * DIN);
            #pragma unroll
            for (int i = 0; i < 4; i++) {
                float4 v = xsrc[i];
                xr[4*i] = v.x; xr[4*i+1] = v.y; xr[4*i+2] = v.z; xr[4*i+3] = v.w;
            }
            unsigned pk[8];
            #pragma unroll
            for (int cc = 0; cc < 16; cc += 2) {
                int c0 = 16 * s + cc;
                float a0 = b0s[c0], a1 = b0s[c0 + 1];
                #pragma unroll
                for (int k = 0; k < DIN; k++) {
                    float2 w = *(const float2*)&W0s[k * DIM + c0];
                    a0 += xr[k] * w.x; a1 += xr[k] * w.y;
                }
                pk[cc >> 1] = f2bf(fmaxf(a0, 0.f)) | (f2bf(fmaxf(a1, 0.f)) << 16);
            }
            *(uint4*)&xs[r * XS_STRIDE + 16 * s] = *(uint4*)&pk[0];
            *(uint4*)&xs[r * XS_STRIDE + 16 * s + 8] = *(uint4*)&pk[4];
        }
        __syncthreads();
        facc_t acc[2][2];
        #pragma unroll
        for (int mt = 0; mt < 2; mt++)
            #pragma unroll
            for (int nt = 0; nt < 2; nt++)
                acc[mt][nt] = (facc_t){bias[nt], bias[nt], bias[nt], bias[nt]};
        #pragma unroll
        for (int kc = 0; kc < 4; kc++) {
            bfrag_t a0 = *(const bfrag_t*)&xs[nn * XS_STRIDE + 32 * kc + 8 * q];
            bfrag_t a1 = *(const bfrag_t*)&xs[(16 + nn) * XS_STRIDE + 32 * kc + 8 * q];
            acc[0][0] = mfma16(a0, B[0][kc], acc[0][0]);
            acc[0][1] = mfma16(a0, B[1][kc], acc[0][1]);
            acc[1][0] = mfma16(a1, B[0][kc], acc[1][0]);
            acc[1][1] = mfma16(a1, B[1][kc], acc[1][1]);
        }
        #pragma unroll
        for (int mt = 0; mt < 2; mt++)
            #pragma unroll
            for (int r = 0; r < 4; r++) {
                int node = n0 + 16 * mt + 4 * q + r;
                #pragma unroll
                for (int nt = 0; nt < 2; nt++)
                    xo[(size_t)node * DIM + 32 * wv + 16 * nt + nn] = acc[mt][nt][r];
            }
    }
}

// ---------------- conv: hs_bf16 = (x @ W_conv) * dinv[node] ----------------

__global__ __launch_bounds__(256) void k_convM(const float* __restrict__ xi,
                                               const float* __restrict__ W,
                                               const float* __restrict__ dinv,
                                               unsigned short* __restrict__ hs) {
    __shared__ short xs[32 * XS_STRIDE];
    int tid = threadIdx.x, lane = tid & 63, wv = tid >> 6;
    bfrag_t B[2][4];
    load_bfrags<DIM, 2>(W, 32 * wv, lane, B);
    int q = lane >> 4, nn = lane & 15;
    const int ngroups = N_NODES / 32;
    for (int g = blockIdx.x; g < ngroups; g += gridDim.x) {
        int n0 = g * 32;
        __syncthreads();
        stage_tile(xi + (size_t)n0 * DIM, xs, tid);
        __syncthreads();
        facc_t acc[2][2] = {};
        #pragma unroll
        for (int kc = 0; kc < 4; kc++) {
            bfrag_t a0 = *(const bfrag_t*)&xs[nn * XS_STRIDE + 32 * kc + 8 * q];
            bfrag_t a1 = *(const bfrag_t*)&xs[(16 + nn) * XS_STRIDE + 32 * kc + 8 * q];
            acc[0][0] = mfma16(a0, B[0][kc], acc[0][0]);
            acc[0][1] = mfma16(a0, B[1][kc], acc[0][1]);
            acc[1][0] = mfma16(a1, B[0][kc], acc[1][0]);
            acc[1][1] = mfma16(a1, B[1][kc], acc[1][1]);
        }
        #pragma unroll
        for (int mt = 0; mt < 2; mt++)
            #pragma unroll
            for (int r = 0; r < 4; r++) {
                int node = n0 + 16 * mt + 4 * q + r;
                float d = dinv[node];
                #pragma unroll
                for (int nt = 0; nt < 2; nt++)
                    hs[(size_t)node * DIM + 32 * wv + 16 * nt + nn] =
                        (unsigned short)f2bf(acc[mt][nt][r] * d);
            }
    }
}

// ---------------- fused gather + residual + bias + LayerNorm ----------------

__global__ __launch_bounds__(256) void k_agg_ln(const unsigned* __restrict__ hs, float* __restrict__ x,
                                                const float* __restrict__ dinv,
                                                const int* __restrict__ indptr,
                                                const int* __restrict__ rows_s,
                                                const float* __restrict__ bconv,
                                                const float* __restrict__ g_, const float* __restrict__ b_) {
    int v = (blockIdx.x * blockDim.x + threadIdx.x) >> 6;
    int lane = threadIdx.x & 63;
    if (v >= N_NODES) return;
    int beg = indptr[v], end = indptr[v + 1];
    float accx, accy;
    { unsigned u = hs[(size_t)v * 64 + lane]; accx = bf_lo(u); accy = bf_hi(u); }  // self loop
    for (int base = beg; base < end; base += 64) {
        int m = end - base; if (m > 64) m = 64;
        int r0 = rows_s[base + (lane < m ? lane : m - 1)];
        int k = 0;
        for (; k + 8 <= m; k += 8) {
            int r[8];
            #pragma unroll
            for (int qq = 0; qq < 8; qq++) r[qq] = __shfl(r0, k + qq);
            unsigned u[8];
            #pragma unroll
            for (int qq = 0; qq < 8; qq++) u[qq] = hs[(size_t)r[qq] * 64 + lane];
            #pragma unroll
            for (int qq = 0; qq < 8; qq++) { accx += bf_lo(u[qq]); accy += bf_hi(u[qq]); }
        }
        for (; k < m; k++) {
            int r = __shfl(r0, k);
            unsigned A = hs[(size_t)r * 64 + lane];
            accx += bf_lo(A); accy += bf_hi(A);
        }
    }
    float dv = dinv[v];
    float2 xv = ((const float2*)x)[(size_t)v * 64 + lane];
    float2 bc = ((const float2*)bconv)[lane];
    float yx = xv.x + dv * accx + bc.x;
    float yy = xv.y + dv * accy + bc.y;
    float s = yx + yy, s2 = yx * yx + yy * yy;
    for (int off = 32; off > 0; off >>= 1) {
        s += __shfl_down(s, off);
        s2 += __shfl_down(s2, off);
    }
    float mu = __shfl(s, 0) * (1.f / 128.f);
    float ms = __shfl(s2, 0) * (1.f / 128.f);
    float rstd = rsqrtf(ms - mu * mu + LN_EPS);
    float2 gg = ((const float2*)g_)[lane];
    float2 bb = ((const float2*)b_)[lane];
    float ox = (yx - mu) * rstd * gg.x + bb.x;
    float oy = (yy - mu) * rstd * gg.y + bb.y;
    ((float2*)x)[(size_t)v * 64 + lane] = make_float2(ox, oy);
}

// ---------------- decoder (fused): out = relu(x@W0+b0)@W1 + b1 ----------------

__global__ __launch_bounds__(256) void k_decM(const float* __restrict__ xi,
                                              const float* __restrict__ W0, const float* __restrict__ b0f,
                                              const float* __restrict__ W1, const float* __restrict__ b1f,
                                              float* __restrict__ out) {
    __shared__ short xs[32 * XS_STRIDE];
    int tid = threadIdx.x, lane = tid & 63, wv = tid >> 6;
    bfrag_t B0[2][4];
    load_bfrags<DIM, 2>(W0, 32 * wv, lane, B0);
    int q = lane >> 4, nn = lane & 15;
    bfrag_t B1[4];
    #pragma unroll
    for (int kc = 0; kc < 4; kc++) {
        int k0 = 32 * kc + 8 * q;
        bfrag_t f;
        #pragma unroll
        for (int j = 0; j < 8; j++)
            f[j] = (__bf16)W1[(size_t)(k0 + j) * DOUT + nn];
        B1[kc] = f;
    }
    float bias0[2] = { b0f[32 * wv + nn], b0f[32 * wv + 16 + nn] };
    float bias1 = b1f[nn];
    const int ngroups = N_NODES / 32;
    for (int g = blockIdx.x; g < ngroups; g += gridDim.x) {
        int n0 = g * 32;
        __syncthreads();
        stage_tile(xi + (size_t)n0 * DIM, xs, tid);
        __syncthreads();
        facc_t acc[2][2];
        #pragma unroll
        for (int mt = 0; mt < 2; mt++)
            #pragma unroll
            for (int nt = 0; nt < 2; nt++)
                acc[mt][nt] = (facc_t){bias0[nt], bias0[nt], bias0[nt], bias0[nt]};
        #pragma unroll
        for (int kc = 0; kc < 4; kc++) {
            bfrag_t a0 = *(const bfrag_t*)&xs[nn * XS_STRIDE + 32 * kc + 8 * q];
            bfrag_t a1 = *(const bfrag_t*)&xs[(16 + nn) * XS_STRIDE + 32 * kc + 8 * q];
            acc[0][0] = mfma16(a0, B0[0][kc], acc[0][0]);
            acc[0][1] = mfma16(a0, B0[1][kc], acc[0][1]);
            acc[1][0] = mfma16(a1, B0[0][kc], acc[1][0]);
            acc[1][1] = mfma16(a1, B0[1][kc], acc[1][1]);
        }
        __syncthreads();   // all A-reads of x-tile done; xs can be overwritten
        #pragma unroll
        for (int mt = 0; mt < 2; mt++)
            #pragma unroll
            for (int nt = 0; nt < 2; nt++)
                #pragma unroll
                for (int r = 0; r < 4; r++) {
                    int nl = 16 * mt + 4 * q + r;
                    int col = 32 * wv + 16 * nt + nn;
                    xs[nl * XS_STRIDE + col] = (short)f2bf(fmaxf(acc[mt][nt][r], 0.f));
                }
        __syncthreads();
        if (wv < 2) {   // waves 0,1: t2[32x128] @ W1[128x16]
            facc_t acc2 = (facc_t){bias1, bias1, bias1, bias1};
            #pragma unroll
            for (int kc = 0; kc < 4; kc++) {
                bfrag_t a = *(const bfrag_t*)&xs[(16 * wv + nn) * XS_STRIDE + 32 * kc + 8 * q];
                acc2 = mfma16(a, B1[kc], acc2);
            }
            #pragma unroll
            for (int r = 0; r < 4; r++) {
                int node = n0 + 16 * wv + 4 * q + r;
                out[(size_t)node * DOUT + nn] = acc2[r];
            }
        }
    }
}

// ---------------- launch ----------------

extern "C" void kernel_launch(void* const* d_in, const int* in_sizes, int n_in,
                              void* d_out, int out_size, void* d_ws, size_t ws_size,
                              hipStream_t stream) {
    const float* X      = (const float*)d_in[0];
    const float* W_enc0 = (const float*)d_in[1];
    const float* b_enc0 = (const float*)d_in[2];
    const float* W_enc1 = (const float*)d_in[3];
    const float* b_enc1 = (const float*)d_in[4];
    const float* W_conv = (const float*)d_in[5];
    const float* b_conv = (const float*)d_in[6];
    const float* ln_g   = (const float*)d_in[7];
    const float* ln_b   = (const float*)d_in[8];
    const float* W_dec0 = (const float*)d_in[9];
    const float* b_dec0 = (const float*)d_in[10];
    const float* W_dec1 = (const float*)d_in[11];
    const float* b_dec1 = (const float*)d_in[12];
    const int*   erow   = (const int*)d_in[13];         // edge_index[0] = sources
    const int*   ecol   = erow + NEDGE;                 // edge_index[1] = targets
    float* out = (float*)d_out;

    float*          x       = (float*)d_ws;                                  // N*128 f32
    unsigned short* hs      = (unsigned short*)(x + (size_t)N_NODES * DIM);  // N*128 bf16
    float*          dinv    = (float*)(hs + (size_t)N_NODES * DIM);          // N f32
    int*            indptr  = (int*)(dinv + N_NODES);                        // N+1 int
    int*            binsize = indptr + N_NODES + 8;                          // NBINS
    int*            binbase = binsize + NBINS + 8;                           // NBINS+1
    int*            bincur  = binbase + NBINS + 9;                           // NBINS
    int*            rows_s  = bincur + NBINS + 8;                            // E int
    unsigned*       pairs   = (unsigned*)hs;   // overlay: build finishes before conv writes hs

    // CSR build (per launch; d_ws is re-poisoned before every call)
    k_zb     <<<1, 512, 0, stream>>>(binsize);
    k_hist   <<<NPB, 256, 0, stream>>>(ecol, binsize);
    k_scanb  <<<1, 512, 0, stream>>>(binsize, binbase, bincur);
    k_binpass<<<NPB, 256, 0, stream>>>(erow, ecol, bincur, pairs);
    k_csr2   <<<NBINS, 256, 0, stream>>>(pairs, binbase, indptr, dinv, rows_s);

    k_encM<<<GGRID, 256, 0, stream>>>(X, W_enc0, b_enc0, W_enc1, b_enc1, x);

    for (int s = 0; s < 3; s++) {   // msg_steps = 3 (fixed scalar input)
        k_convM<<<GGRID, 256, 0, stream>>>(x, W_conv, dinv, hs);
        k_agg_ln<<<N_NODES / 4, 256, 0, stream>>>((const unsigned*)hs, x, dinv, indptr, rows_s,
                                                  b_conv, ln_g, ln_b);
    }

    k_decM<<<GGRID, 256, 0, stream>>>(x, W_dec0, b_dec0, W_dec1, b_dec1, out);
}